// Round 1
// 340.383 us; speedup vs baseline: 1.4061x; 1.4061x over previous
//
#include <hip/hip_runtime.h>
#include <hip/hip_bf16.h>
#include <math.h>

constexpr int SEQ   = 512;
constexpr int HIDC  = 1024;
constexpr int NH    = 16;
constexpr int HDIM  = 64;
constexpr int NFREQ = 33;   // rfft bins for n=64
constexpr int NF2V  = 66;   // packed (Re|Im) length

typedef unsigned short u16;
typedef __bf16 bf16x8 __attribute__((ext_vector_type(8)));
typedef float  f32x4  __attribute__((ext_vector_type(4)));

// dtype-agnostic input load: f32 ? float : bf16
__device__ __forceinline__ float ldin(const void* p, int i, int f32) {
    if (f32) return ((const float*)p)[i];
    return __bfloat162float(((const __hip_bfloat16*)p)[i]);
}

__device__ __forceinline__ u16 f2b(float f) {   // RNE fp32 -> bf16 bits
    unsigned int u = __builtin_bit_cast(unsigned int, f);
    u += 0x7fffu + ((u >> 16) & 1u);
    return (u16)(u >> 16);
}

// ---------------- K0: dtype sniff ----------------
__global__ void sniff_kernel(const void* w, int* flag) {
    __shared__ int cnt;
    if (threadIdx.x == 0) cnt = 0;
    __syncthreads();
    const unsigned short* h = (const unsigned short*)w;
    int bad = 0;
    for (int i = threadIdx.x; i < 512; i += 256) {
        const unsigned short v = h[i];
        const int ex = (v >> 7) & 0xFF;   // bf16 exponent field
        if (ex >= 134) bad++;             // |x| >= 128 (or inf/nan)
    }
    atomicAdd(&cnt, bad);
    __syncthreads();
    if (threadIdx.x == 0) flag[0] = (cnt > 32) ? 1 : 0;
}

// ======================================================================
// bf16 MFMA path (runs when flag == 0)
// ======================================================================

// ---- W transpose: Wt[n][k] = W[k][n], bf16 bits, 64x64 LDS tiles ----
__global__ __launch_bounds__(256) void wtr_kernel(
    const void* __restrict__ W0, const void* __restrict__ W1,
    const void* __restrict__ W2, const void* __restrict__ W3,
    u16* __restrict__ Wt0, u16* __restrict__ Wt1,
    u16* __restrict__ Wt2, u16* __restrict__ Wt3,
    const int* __restrict__ flagp)
{
    if (*flagp != 0) return;
    __shared__ u16 t[64][65];
    const int mz = blockIdx.z;
    const u16* W = (const u16*)(mz == 0 ? W0 : mz == 1 ? W1 : mz == 2 ? W2 : W3);
    u16* Wt = (mz == 0 ? Wt0 : mz == 1 ? Wt1 : mz == 2 ? Wt2 : Wt3);
    const int n0 = blockIdx.x * 64, k0 = blockIdx.y * 64;
    const int tid = threadIdx.x;
    #pragma unroll
    for (int i = 0; i < 4; ++i) {
        const int item = i * 256 + tid;
        const int r = item >> 4, c4 = (item & 15) * 4;
        const ushort4 v = *(const ushort4*)&W[(k0 + r) * HIDC + n0 + c4];
        t[r][c4 + 0] = v.x; t[r][c4 + 1] = v.y; t[r][c4 + 2] = v.z; t[r][c4 + 3] = v.w;
    }
    __syncthreads();
    #pragma unroll
    for (int i = 0; i < 4; ++i) {
        const int item = i * 256 + tid;
        const int r = item >> 4, c4 = (item & 15) * 4;
        ushort4 o;
        o.x = t[c4 + 0][r]; o.y = t[c4 + 1][r]; o.z = t[c4 + 2][r]; o.w = t[c4 + 3][r];
        *(ushort4*)&Wt[(n0 + r) * HIDC + k0 + c4] = o;
    }
}

// ---- fp32 -> bf16 convert (ctx before O-proj) ----
__global__ __launch_bounds__(256) void cvt_kernel(
    const float* __restrict__ src, u16* __restrict__ dst,
    const int* __restrict__ flagp)
{
    if (*flagp != 0) return;
    const int i = blockIdx.x * 1024 + threadIdx.x * 4;
    const float4 v = *(const float4*)&src[i];
    ushort4 o;
    o.x = f2b(v.x); o.y = f2b(v.y); o.z = f2b(v.z); o.w = f2b(v.w);
    *(ushort4*)&dst[i] = o;
}

// ---- MFMA GEMM: C[64x128 tile] = A[512x1024] @ Bt^T (Bt is [n][k]) ----
// MODE 0: QKV (grid.x = 24 spans Q|K|V col-blocks), out = acc + bias
// MODE 1: O-proj (grid.x = 8), out = acc + bias + residual(x)
template <int MODE>
__global__ __launch_bounds__(256) void mfma_gemm_kernel(
    const u16* __restrict__ A,
    const u16* __restrict__ Bt0, const u16* __restrict__ Bt1, const u16* __restrict__ Bt2,
    const void* __restrict__ b0, const void* __restrict__ b1, const void* __restrict__ b2,
    const void* __restrict__ xres,
    float* __restrict__ O0, float* __restrict__ O1, float* __restrict__ O2,
    const int* __restrict__ flagp)
{
    if (*flagp != 0) return;
    __shared__ __align__(16) u16 smem[(64 + 128) * 64];   // A: [64][64], B: [128][64]

    const int tid  = threadIdx.x;
    const int lane = tid & 63, wv = tid >> 6;
    const int m0 = blockIdx.y * 64;
    const int n0 = blockIdx.x * 128;

    const u16* Bsel; const void* bias; float* Out; int col0;
    if (MODE == 0) {
        const int mat = n0 >> 10;
        col0 = n0 & 1023;
        Bsel = (mat == 0) ? Bt0 : (mat == 1) ? Bt1 : Bt2;
        bias = (mat == 0) ? b0  : (mat == 1) ? b1  : b2;
        Out  = (mat == 0) ? O0  : (mat == 1) ? O1  : O2;
    } else {
        col0 = n0; Bsel = Bt0; bias = b0; Out = O0;
    }

    // --- staging: per thread 2 A-chunks + 4 B-chunks of 16B per K-step ---
    const int srow = tid >> 3;          // 0..31
    const int sg   = tid & 7;           // 16B granule within 128B row
    int aw[2], bw[4];
    #pragma unroll
    for (int i = 0; i < 2; ++i) { const int r = srow + i * 32; aw[i] = r * 64 + ((sg ^ (r & 7)) * 8); }
    #pragma unroll
    for (int i = 0; i < 4; ++i) { const int r = srow + i * 32; bw[i] = 64 * 64 + r * 64 + ((sg ^ (r & 7)) * 8); }
    const u16* gA = A    + (m0   + srow) * HIDC + sg * 8;
    const u16* gB = Bsel + (col0 + srow) * HIDC + sg * 8;

    // --- fragment read offsets (swizzle-consistent) ---
    int g16[2];
    #pragma unroll
    for (int kc = 0; kc < 2; ++kc) g16[kc] = (((kc * 4) + (lane >> 4)) ^ (lane & 7)) * 8;
    int afo[4], bfo[2];
    #pragma unroll
    for (int mi = 0; mi < 4; ++mi) afo[mi] = (mi * 16 + (lane & 15)) * 64;
    #pragma unroll
    for (int ni = 0; ni < 2; ++ni) bfo[ni] = 64 * 64 + (wv * 32 + ni * 16 + (lane & 15)) * 64;

    f32x4 zero = {0.f, 0.f, 0.f, 0.f};
    f32x4 acc[4][2];
    #pragma unroll
    for (int mi = 0; mi < 4; ++mi)
        #pragma unroll
        for (int ni = 0; ni < 2; ++ni) acc[mi][ni] = zero;

    uint4 ra[2], rb[4];
    #pragma unroll
    for (int i = 0; i < 2; ++i) ra[i] = *(const uint4*)(gA + i * 32 * HIDC);
    #pragma unroll
    for (int i = 0; i < 4; ++i) rb[i] = *(const uint4*)(gB + i * 32 * HIDC);

    for (int t = 0; t < 16; ++t) {
        __syncthreads();                       // prev step's frag reads done
        #pragma unroll
        for (int i = 0; i < 2; ++i) *(uint4*)(smem + aw[i]) = ra[i];
        #pragma unroll
        for (int i = 0; i < 4; ++i) *(uint4*)(smem + bw[i]) = rb[i];
        __syncthreads();
        if (t < 15) {
            const int k = (t + 1) * 64;
            #pragma unroll
            for (int i = 0; i < 2; ++i) ra[i] = *(const uint4*)(gA + i * 32 * HIDC + k);
            #pragma unroll
            for (int i = 0; i < 4; ++i) rb[i] = *(const uint4*)(gB + i * 32 * HIDC + k);
        }
        #pragma unroll
        for (int kc = 0; kc < 2; ++kc) {
            bf16x8 af[4], bfr[2];
            #pragma unroll
            for (int mi = 0; mi < 4; ++mi) af[mi]  = *(const bf16x8*)(smem + afo[mi] + g16[kc]);
            #pragma unroll
            for (int ni = 0; ni < 2; ++ni) bfr[ni] = *(const bf16x8*)(smem + bfo[ni] + g16[kc]);
            #pragma unroll
            for (int mi = 0; mi < 4; ++mi)
                #pragma unroll
                for (int ni = 0; ni < 2; ++ni)
                    acc[mi][ni] = __builtin_amdgcn_mfma_f32_16x16x32_bf16(
                        af[mi], bfr[ni], acc[mi][ni], 0, 0, 0);
        }
    }

    // --- epilogue: D row = (lane>>4)*4 + r, col = lane&15 (m89-verified) ---
    #pragma unroll
    for (int ni = 0; ni < 2; ++ni) {
        const int col = col0 + wv * 32 + ni * 16 + (lane & 15);
        const float bval = ldin(bias, col, 0);
        #pragma unroll
        for (int mi = 0; mi < 4; ++mi) {
            const int row0 = m0 + mi * 16 + (lane >> 4) * 4;
            #pragma unroll
            for (int r = 0; r < 4; ++r) {
                const int row = row0 + r;
                float v = acc[mi][ni][r] + bval;
                if (MODE == 1) v += ldin(xres, row * HIDC + col, 0);
                Out[row * HIDC + col] = v;
            }
        }
    }
}

// ======================================================================
// fp32 fallback path (runs when flag == 1) — unchanged VALU GEMMs
// ======================================================================

__global__ __launch_bounds__(256) void qkv_kernel(
    const void* __restrict__ x,
    const void* __restrict__ Wq, const void* __restrict__ bq,
    const void* __restrict__ Wk, const void* __restrict__ bk,
    const void* __restrict__ Wv, const void* __restrict__ bv,
    float* __restrict__ Q, float* __restrict__ K, float* __restrict__ V,
    const int* __restrict__ flagp)
{
    const int F = *flagp;
    if (F != 1) return;
    __shared__ float As[64][17];
    __shared__ float Bs[16][65];
    const int tid = threadIdx.x;
    const int n0  = blockIdx.x * 64;
    const int m0  = blockIdx.y * 64;
    const int mat = n0 >> 10;
    const int col0 = n0 & 1023;
    const void* W    = (mat == 0) ? Wq : (mat == 1) ? Wk : Wv;
    const void* bias = (mat == 0) ? bq : (mat == 1) ? bk : bv;
    float* Out = (mat == 0) ? Q : (mat == 1) ? K : V;

    const int tx = tid & 15, ty = tid >> 4;
    float acc[4][4] = {};

    for (int k0 = 0; k0 < HIDC; k0 += 16) {
        {
            const int r  = tid >> 2;
            const int kk = (tid & 3) * 4;
            const int base = (m0 + r) * HIDC + k0 + kk;
            #pragma unroll
            for (int j = 0; j < 4; ++j) As[r][kk + j] = ldin(x, base + j, F);
        }
        {
            const int c  = tid & 63;
            const int kb = tid >> 6;
            #pragma unroll
            for (int j = 0; j < 4; ++j) {
                const int kk = kb + j * 4;
                Bs[kk][c] = ldin(W, (k0 + kk) * HIDC + col0 + c, F);
            }
        }
        __syncthreads();
        #pragma unroll
        for (int kk = 0; kk < 16; ++kk) {
            float a[4], b[4];
            #pragma unroll
            for (int i = 0; i < 4; ++i) a[i] = As[ty * 4 + i][kk];
            #pragma unroll
            for (int j = 0; j < 4; ++j) b[j] = Bs[kk][tx * 4 + j];
            #pragma unroll
            for (int i = 0; i < 4; ++i)
                #pragma unroll
                for (int j = 0; j < 4; ++j)
                    acc[i][j] = fmaf(a[i], b[j], acc[i][j]);
        }
        __syncthreads();
    }
    #pragma unroll
    for (int i = 0; i < 4; ++i) {
        const int m = m0 + ty * 4 + i;
        #pragma unroll
        for (int j = 0; j < 4; ++j) {
            const int c = col0 + tx * 4 + j;
            Out[m * HIDC + c] = acc[i][j] + ldin(bias, c, F);
        }
    }
}

__global__ __launch_bounds__(256) void oproj_kernel(
    const float* __restrict__ A, const void* __restrict__ W,
    const void* __restrict__ bias, const void* __restrict__ x,
    float* __restrict__ Y, const int* __restrict__ flagp)
{
    const int F = *flagp;
    if (F != 1) return;
    __shared__ float As[64][17];
    __shared__ float Bs[16][65];
    const int tid = threadIdx.x;
    const int n0 = blockIdx.x * 64;
    const int m0 = blockIdx.y * 64;
    const int tx = tid & 15, ty = tid >> 4;
    float acc[4][4] = {};

    for (int k0 = 0; k0 < HIDC; k0 += 16) {
        {
            const int r  = tid >> 2;
            const int kk = (tid & 3) * 4;
            const float* ap = A + (m0 + r) * HIDC + k0 + kk;
            #pragma unroll
            for (int j = 0; j < 4; ++j) As[r][kk + j] = ap[j];
        }
        {
            const int c  = tid & 63;
            const int kb = tid >> 6;
            #pragma unroll
            for (int j = 0; j < 4; ++j) {
                const int kk = kb + j * 4;
                Bs[kk][c] = ldin(W, (k0 + kk) * HIDC + n0 + c, F);
            }
        }
        __syncthreads();
        #pragma unroll
        for (int kk = 0; kk < 16; ++kk) {
            float a[4], b[4];
            #pragma unroll
            for (int i = 0; i < 4; ++i) a[i] = As[ty * 4 + i][kk];
            #pragma unroll
            for (int j = 0; j < 4; ++j) b[j] = Bs[kk][tx * 4 + j];
            #pragma unroll
            for (int i = 0; i < 4; ++i)
                #pragma unroll
                for (int j = 0; j < 4; ++j)
                    acc[i][j] = fmaf(a[i], b[j], acc[i][j]);
        }
        __syncthreads();
    }
    #pragma unroll
    for (int i = 0; i < 4; ++i) {
        const int m = m0 + ty * 4 + i;
        #pragma unroll
        for (int j = 0; j < 4; ++j) {
            const int c = n0 + tx * 4 + j;
            Y[m * HIDC + c] = acc[i][j] + ldin(bias, c, F) + ldin(x, m * HIDC + c, F);
        }
    }
}

// ---------------- K2: rfft(64) + amplitude normalization ----------------
__global__ __launch_bounds__(64) void spectral_kernel(
    const float* __restrict__ Q, const float* __restrict__ K,
    float* __restrict__ Qn, float* __restrict__ Kn)
{
    __shared__ float qv[64];
    __shared__ float tc[64], tsn[64];
    const int unit = blockIdx.x;          // s*16 + h
    const int sel  = blockIdx.y;          // 0: Q, 1: K
    const int s = unit >> 4, h = unit & 15;
    const float* src = sel ? K : Q;
    float* dst = sel ? Kn : Qn;
    const int t = threadIdx.x;

    qv[t] = src[s * HIDC + h * HDIM + t];
    float sv, cv;
    sincosf((float)t * (6.283185307179586f / 64.0f), &sv, &cv);
    tc[t] = cv; tsn[t] = sv;
    __syncthreads();

    if (t < NFREQ) {
        float re = 0.0f, im = 0.0f;
        #pragma unroll
        for (int k = 0; k < 64; ++k) {
            const int idx = (t * k) & 63;
            re = fmaf(qv[k], tc[idx], re);
            im = fmaf(qv[k], -tsn[idx], im);
        }
        const float a  = sqrtf(re * re + im * im);
        const float sc = (a > 0.0f) ? rsqrtf(a) : 0.0f;
        const int base = (h * SEQ + s) * NF2V;
        dst[base + t]         = re * sc;
        dst[base + NFREQ + t] = im * sc;
    }
}

// ---------------- K3: attention ----------------
__global__ __launch_bounds__(256) void attn_kernel(
    const float* __restrict__ Qn, const float* __restrict__ Kn,
    const float* __restrict__ V, const int* __restrict__ mask,
    const void* __restrict__ temp_p, float* __restrict__ ctx,
    const int* __restrict__ flagp)
{
    __shared__ float qn[8][NF2V];
    __shared__ float sc[8][SEQ];
    __shared__ float kt[64 * 67];
    __shared__ float red[4][8][64];
    __shared__ float rowsum[8];

    const int F   = *flagp;
    const int tid = threadIdx.x;
    const int h   = blockIdx.y;
    const int q0  = blockIdx.x * 8;
    const float temp = ldin(temp_p, 0, F);

    for (int idx = tid; idx < 8 * NF2V; idx += 256) {
        const int r = idx / NF2V, f = idx % NF2V;
        qn[r][f] = Qn[(h * SEQ + q0 + r) * NF2V + f];
    }
    __syncthreads();

    for (int kt0 = 0; kt0 < SEQ; kt0 += 64) {
        for (int idx = tid; idx < 64 * NF2V; idx += 256) {
            const int kk = idx / NF2V, f = idx % NF2V;
            kt[kk * 67 + f] = Kn[(h * SEQ + kt0 + kk) * NF2V + f];
        }
        __syncthreads();
        #pragma unroll
        for (int it = 0; it < 2; ++it) {
            const int item = tid + it * 256;
            const int r = item >> 6, kk = item & 63;
            float d = 0.0f;
            #pragma unroll
            for (int f = 0; f < NF2V; ++f) d = fmaf(qn[r][f], kt[kk * 67 + f], d);
            const int kabs = kt0 + kk;
            float sco = d * temp;
            if (mask[kabs] == 0) sco = -1e9f;
            sc[r][kabs] = sco;
        }
        __syncthreads();
    }

    const int w = tid >> 6, lane = tid & 63;
    for (int rr = 0; rr < 2; ++rr) {
        const int r = w * 2 + rr;
        float m = -1e30f;
        for (int k = lane; k < SEQ; k += 64) m = fmaxf(m, sc[r][k]);
        #pragma unroll
        for (int off = 32; off > 0; off >>= 1) m = fmaxf(m, __shfl_xor(m, off, 64));
        float sum = 0.0f;
        for (int k = lane; k < SEQ; k += 64) {
            const float e = __expf(sc[r][k] - m);
            sc[r][k] = e;
            sum += e;
        }
        #pragma unroll
        for (int off = 32; off > 0; off >>= 1) sum += __shfl_xor(sum, off, 64);
        if (lane == 0) rowsum[r] = sum;
    }
    __syncthreads();

    {
        const int d = tid & 63, c = tid >> 6;
        float acc[8] = {};
        const float* vcol = V + h * HDIM + d;
        for (int k = c * 128; k < c * 128 + 128; ++k) {
            const float v = vcol[k * HIDC];
            #pragma unroll
            for (int r = 0; r < 8; ++r) acc[r] = fmaf(sc[r][k], v, acc[r]);
        }
        #pragma unroll
        for (int r = 0; r < 8; ++r) red[c][r][d] = acc[r];
    }
    __syncthreads();
    #pragma unroll
    for (int p = 0; p < 2; ++p) {
        const int item = tid + p * 256;
        const int r = item >> 6, dd = item & 63;
        const float sum4 = red[0][r][dd] + red[1][r][dd] + red[2][r][dd] + red[3][r][dd];
        ctx[(q0 + r) * HIDC + h * HDIM + dd] = sum4 / rowsum[r];
    }
}

// ---------------- K5: LayerNorm -> out ----------------
__global__ __launch_bounds__(256) void ln_kernel(
    const float* __restrict__ Y, const void* __restrict__ gamma,
    const void* __restrict__ beta, void* __restrict__ out,
    const int* __restrict__ flagp)
{
    const int F = *flagp;
    const int row = blockIdx.x, tid = threadIdx.x;
    float v[4];
    float s = 0.0f, s2 = 0.0f;
    #pragma unroll
    for (int j = 0; j < 4; ++j) {
        v[j] = Y[row * HIDC + tid + j * 256];
        s += v[j]; s2 += v[j] * v[j];
    }
    #pragma unroll
    for (int off = 32; off > 0; off >>= 1) {
        s  += __shfl_xor(s, off, 64);
        s2 += __shfl_xor(s2, off, 64);
    }
    __shared__ float wred[4][2];
    const int w = tid >> 6;
    if ((tid & 63) == 0) { wred[w][0] = s; wred[w][1] = s2; }
    __syncthreads();
    s  = wred[0][0] + wred[1][0] + wred[2][0] + wred[3][0];
    s2 = wred[0][1] + wred[1][1] + wred[2][1] + wred[3][1];
    const float mu   = s / (float)HIDC;
    const float var  = s2 / (float)HIDC - mu * mu;
    const float rstd = rsqrtf(var + 1e-5f);
    #pragma unroll
    for (int j = 0; j < 4; ++j) {
        const int c = tid + j * 256;
        const float g = ldin(gamma, c, F), b = ldin(beta, c, F);
        const float r = (v[j] - mu) * rstd * g + b;
        if (F) ((float*)out)[row * HIDC + c] = r;
        else   ((__hip_bfloat16*)out)[row * HIDC + c] = __float2bfloat16(r);
    }
}

extern "C" void kernel_launch(void* const* d_in, const int* in_sizes, int n_in,
                              void* d_out, int out_size, void* d_ws, size_t ws_size,
                              hipStream_t stream) {
    const void* x    = d_in[0];
    const int*  mask = (const int*)d_in[1];
    const void* Wq   = d_in[2];
    const void* bq   = d_in[3];
    const void* Wk   = d_in[4];
    const void* bk   = d_in[5];
    const void* Wv   = d_in[6];
    const void* bv   = d_in[7];
    const void* Wo   = d_in[8];
    const void* bo   = d_in[9];
    const void* temp = d_in[10];
    const void* gam  = d_in[11];
    const void* bet  = d_in[12];

    float* ws   = (float*)d_ws;
    int*   flag = (int*)ws;                  // 16B reserved
    float* Q    = ws + 4;                    // 512*1024 f32
    float* K    = Q   + SEQ * HIDC;
    float* V    = K   + SEQ * HIDC;
    float* Qn   = V   + SEQ * HIDC;          // 16*512*66 f32
    float* Kn   = Qn  + NH * SEQ * NF2V;
    float* ctx  = Kn  + NH * SEQ * NF2V;     // 512*1024 f32
    float* Y    = ctx + SEQ * HIDC;          // 512*1024 f32
    u16*   ctxb = (u16*)(Y + SEQ * HIDC);    // 512*1024 bf16
    u16*   Wtq  = ctxb + SEQ * HIDC;         // 4 x 1024*1024 bf16
    u16*   Wtk  = Wtq + HIDC * HIDC;
    u16*   Wtv  = Wtk + HIDC * HIDC;
    u16*   Wto  = Wtv + HIDC * HIDC;

    sniff_kernel<<<1, 256, 0, stream>>>(Wq, flag);

    // bf16 path prep (no-op in fp32 mode)
    wtr_kernel<<<dim3(16, 16, 4), 256, 0, stream>>>(Wq, Wk, Wv, Wo, Wtq, Wtk, Wtv, Wto, flag);

    // QKV projection — dual path
    qkv_kernel<<<dim3(48, 8), 256, 0, stream>>>(x, Wq, bq, Wk, bk, Wv, bv, Q, K, V, flag);
    mfma_gemm_kernel<0><<<dim3(24, 8), 256, 0, stream>>>(
        (const u16*)x, Wtq, Wtk, Wtv, bq, bk, bv, nullptr, Q, K, V, flag);

    spectral_kernel<<<dim3(SEQ * NH, 2), 64, 0, stream>>>(Q, K, Qn, Kn);
    attn_kernel<<<dim3(SEQ / 8, NH), 256, 0, stream>>>(Qn, Kn, V, mask, temp, ctx, flag);

    // O-projection — dual path
    cvt_kernel<<<512, 256, 0, stream>>>(ctx, ctxb, flag);
    oproj_kernel<<<dim3(16, 8), 256, 0, stream>>>(ctx, Wo, bo, x, Y, flag);
    mfma_gemm_kernel<1><<<dim3(8, 8), 256, 0, stream>>>(
        ctxb, Wto, nullptr, nullptr, bo, nullptr, nullptr, x, Y, nullptr, nullptr, flag);

    ln_kernel<<<SEQ, 256, 0, stream>>>(Y, gam, bet, d_out, flag);
}

// Round 2
// 322.416 us; speedup vs baseline: 1.4845x; 1.0557x over previous
//
#include <hip/hip_runtime.h>
#include <hip/hip_bf16.h>
#include <math.h>

constexpr int SEQ   = 512;
constexpr int HIDC  = 1024;
constexpr int NH    = 16;
constexpr int HDIM  = 64;
constexpr int NFREQ = 33;   // rfft bins for n=64
constexpr int NF2V  = 66;   // packed (Re|Im) length

typedef unsigned short u16;
typedef __bf16 bf16x8 __attribute__((ext_vector_type(8)));
typedef float  f32x4  __attribute__((ext_vector_type(4)));

// dtype-agnostic input load: f32 ? float : bf16
__device__ __forceinline__ float ldin(const void* p, int i, int f32) {
    if (f32) return ((const float*)p)[i];
    return __bfloat162float(((const __hip_bfloat16*)p)[i]);
}

__device__ __forceinline__ u16 f2b(float f) {   // RNE fp32 -> bf16 bits
    unsigned int u = __builtin_bit_cast(unsigned int, f);
    u += 0x7fffu + ((u >> 16) & 1u);
    return (u16)(u >> 16);
}
__device__ __forceinline__ float b2f(u16 b) {
    return __builtin_bit_cast(float, (unsigned int)b << 16);
}
// fp32 -> (hi, lo) bf16 pair; hi + lo ~ f to ~16 mantissa bits
__device__ __forceinline__ void split2(float f, u16& hi, u16& lo) {
    hi = f2b(f);
    lo = f2b(f - b2f(hi));
}

// ---------------- K0: dtype sniff ----------------
// bf16 data has small exponents; fp32 reinterpreted as bf16 halves shows
// ~half the halfwords with huge exponents.
__global__ void sniff_kernel(const void* w, int* flag) {
    __shared__ int cnt;
    if (threadIdx.x == 0) cnt = 0;
    __syncthreads();
    const unsigned short* h = (const unsigned short*)w;
    int bad = 0;
    for (int i = threadIdx.x; i < 512; i += 256) {
        const unsigned short v = h[i];
        const int ex = (v >> 7) & 0xFF;   // bf16 exponent field
        if (ex >= 134) bad++;             // |x| >= 128 (or inf/nan)
    }
    atomicAdd(&cnt, bad);
    __syncthreads();
    if (threadIdx.x == 0) flag[0] = (cnt > 32) ? 1 : 0;
}

// ---------------- K1a: W transpose + hi/lo split ----------------
// W[k][n] (dtype per flag) -> Wthi[n][k], Wtlo[n][k] (bf16 bits)
__global__ __launch_bounds__(256) void wsplit_kernel(
    const void* __restrict__ W0, const void* __restrict__ W1,
    const void* __restrict__ W2, const void* __restrict__ W3,
    u16* __restrict__ H0, u16* __restrict__ L0,
    u16* __restrict__ H1, u16* __restrict__ L1,
    u16* __restrict__ H2, u16* __restrict__ L2,
    u16* __restrict__ H3, u16* __restrict__ L3,
    const int* __restrict__ flagp)
{
    __shared__ float t[64][65];
    const int F  = *flagp;
    const int mz = blockIdx.z;
    const void* W = (mz == 0) ? W0 : (mz == 1) ? W1 : (mz == 2) ? W2 : W3;
    u16* H = (mz == 0) ? H0 : (mz == 1) ? H1 : (mz == 2) ? H2 : H3;
    u16* L = (mz == 0) ? L0 : (mz == 1) ? L1 : (mz == 2) ? L2 : L3;
    const int n0 = blockIdx.x * 64, k0 = blockIdx.y * 64;
    const int tid = threadIdx.x;

    #pragma unroll
    for (int i = 0; i < 4; ++i) {
        const int item = i * 256 + tid;
        const int r = item >> 4, c4 = (item & 15) * 4;
        if (F) {
            const float4 v = *(const float4*)((const float*)W + (k0 + r) * HIDC + n0 + c4);
            t[r][c4 + 0] = v.x; t[r][c4 + 1] = v.y; t[r][c4 + 2] = v.z; t[r][c4 + 3] = v.w;
        } else {
            #pragma unroll
            for (int j = 0; j < 4; ++j)
                t[r][c4 + j] = ldin(W, (k0 + r) * HIDC + n0 + c4 + j, 0);
        }
    }
    __syncthreads();
    #pragma unroll
    for (int i = 0; i < 4; ++i) {
        const int item = i * 256 + tid;
        const int r = item >> 4, c4 = (item & 15) * 4;   // r: n-offset, c4: k-offset
        ushort4 oh, ol;
        u16 h, l;
        split2(t[c4 + 0][r], h, l); oh.x = h; ol.x = l;
        split2(t[c4 + 1][r], h, l); oh.y = h; ol.y = l;
        split2(t[c4 + 2][r], h, l); oh.z = h; ol.z = l;
        split2(t[c4 + 3][r], h, l); oh.w = h; ol.w = l;
        *(ushort4*)&H[(n0 + r) * HIDC + k0 + c4] = oh;
        *(ushort4*)&L[(n0 + r) * HIDC + k0 + c4] = ol;
    }
}

// ---------------- K1b: activation hi/lo split (x or ctx) ----------------
__global__ __launch_bounds__(256) void xsplit_kernel(
    const void* __restrict__ src, u16* __restrict__ hi, u16* __restrict__ lo,
    const int* __restrict__ flagp, int force_f32)
{
    const int F = force_f32 ? 1 : *flagp;
    const int i = blockIdx.x * 1024 + threadIdx.x * 4;
    float v[4];
    if (F) {
        const float4 f = *(const float4*)((const float*)src + i);
        v[0] = f.x; v[1] = f.y; v[2] = f.z; v[3] = f.w;
    } else {
        #pragma unroll
        for (int j = 0; j < 4; ++j) v[j] = ldin(src, i + j, 0);
    }
    ushort4 oh, ol;
    u16 h, l;
    split2(v[0], h, l); oh.x = h; ol.x = l;
    split2(v[1], h, l); oh.y = h; ol.y = l;
    split2(v[2], h, l); oh.z = h; ol.z = l;
    split2(v[3], h, l); oh.w = h; ol.w = l;
    *(ushort4*)&hi[i] = oh;
    *(ushort4*)&lo[i] = ol;
}

// ---------------- K1c: 3-term split-bf16 MFMA GEMM ----------------
// C = (Ahi+Alo) @ (Bhi+Blo)^T  ~= Ahi@Bhi + Ahi@Blo + Alo@Bhi   (fp32 acc)
// A: [512][1024] bf16 pair; Bt: [n][k] bf16 pair.
// MODE 0: QKV (grid.x = 24 spans Q|K|V col-blocks), out = acc + bias
// MODE 1: O-proj (grid.x = 8), out = acc + bias + residual(x)
template <int MODE>
__global__ __launch_bounds__(256) void mfma3_gemm_kernel(
    const u16* __restrict__ Ahi, const u16* __restrict__ Alo,
    const u16* __restrict__ B0h, const u16* __restrict__ B0l,
    const u16* __restrict__ B1h, const u16* __restrict__ B1l,
    const u16* __restrict__ B2h, const u16* __restrict__ B2l,
    const void* __restrict__ b0, const void* __restrict__ b1, const void* __restrict__ b2,
    const void* __restrict__ xres,
    float* __restrict__ O0, float* __restrict__ O1, float* __restrict__ O2,
    const int* __restrict__ flagp)
{
    // LDS: AH[64][64] @0, AL @4096, BH[128][64] @8192, BL @16384 (u16 units)
    __shared__ __align__(16) u16 smem[24576];
    const int F    = *flagp;
    const int tid  = threadIdx.x;
    const int lane = tid & 63, wv = tid >> 6;
    const int m0 = blockIdx.y * 64;
    const int n0 = blockIdx.x * 128;

    const u16 *Bh, *Bl; const void* bias; float* Out; int col0;
    if (MODE == 0) {
        const int mat = n0 >> 10;
        col0 = n0 & 1023;
        Bh   = (mat == 0) ? B0h : (mat == 1) ? B1h : B2h;
        Bl   = (mat == 0) ? B0l : (mat == 1) ? B1l : B2l;
        bias = (mat == 0) ? b0  : (mat == 1) ? b1  : b2;
        Out  = (mat == 0) ? O0  : (mat == 1) ? O1  : O2;
    } else {
        col0 = n0; Bh = B0h; Bl = B0l; bias = b0; Out = O0;
    }

    // --- staging addresses: 16B granules, XOR swizzle g ^= (row&7) ---
    const int srow = tid >> 3;          // 0..31
    const int sg   = tid & 7;           // granule within 128B row
    int aw[2], bw[4];
    #pragma unroll
    for (int i = 0; i < 2; ++i) { const int r = srow + i * 32; aw[i] = r * 64 + ((sg ^ (r & 7)) * 8); }
    #pragma unroll
    for (int i = 0; i < 4; ++i) { const int r = srow + i * 32; bw[i] = r * 64 + ((sg ^ (r & 7)) * 8); }
    const u16* gAh = Ahi + (m0   + srow) * HIDC + sg * 8;
    const u16* gAl = Alo + (m0   + srow) * HIDC + sg * 8;
    const u16* gBh = Bh  + (col0 + srow) * HIDC + sg * 8;
    const u16* gBl = Bl  + (col0 + srow) * HIDC + sg * 8;

    // --- fragment read offsets (swizzle-consistent) ---
    int g16[2];
    #pragma unroll
    for (int kc = 0; kc < 2; ++kc) g16[kc] = (((kc * 4) + (lane >> 4)) ^ (lane & 7)) * 8;
    int afo[4], bfo[2];
    #pragma unroll
    for (int mi = 0; mi < 4; ++mi) afo[mi] = (mi * 16 + (lane & 15)) * 64;
    #pragma unroll
    for (int ni = 0; ni < 2; ++ni) bfo[ni] = (wv * 32 + ni * 16 + (lane & 15)) * 64;

    f32x4 zero = {0.f, 0.f, 0.f, 0.f};
    f32x4 acc[4][2];
    #pragma unroll
    for (int mi = 0; mi < 4; ++mi)
        #pragma unroll
        for (int ni = 0; ni < 2; ++ni) acc[mi][ni] = zero;

    uint4 rah[2], ral[2], rbh[4], rbl[4];
    #pragma unroll
    for (int i = 0; i < 2; ++i) { rah[i] = *(const uint4*)(gAh + i * 32 * HIDC);
                                  ral[i] = *(const uint4*)(gAl + i * 32 * HIDC); }
    #pragma unroll
    for (int i = 0; i < 4; ++i) { rbh[i] = *(const uint4*)(gBh + i * 32 * HIDC);
                                  rbl[i] = *(const uint4*)(gBl + i * 32 * HIDC); }

    for (int t = 0; t < 16; ++t) {
        __syncthreads();                       // prev step's frag reads done
        #pragma unroll
        for (int i = 0; i < 2; ++i) { *(uint4*)(smem +         aw[i]) = rah[i];
                                      *(uint4*)(smem +  4096 + aw[i]) = ral[i]; }
        #pragma unroll
        for (int i = 0; i < 4; ++i) { *(uint4*)(smem +  8192 + bw[i]) = rbh[i];
                                      *(uint4*)(smem + 16384 + bw[i]) = rbl[i]; }
        __syncthreads();
        if (t < 15) {
            const int k = (t + 1) * 64;
            #pragma unroll
            for (int i = 0; i < 2; ++i) { rah[i] = *(const uint4*)(gAh + i * 32 * HIDC + k);
                                          ral[i] = *(const uint4*)(gAl + i * 32 * HIDC + k); }
            #pragma unroll
            for (int i = 0; i < 4; ++i) { rbh[i] = *(const uint4*)(gBh + i * 32 * HIDC + k);
                                          rbl[i] = *(const uint4*)(gBl + i * 32 * HIDC + k); }
        }
        #pragma unroll
        for (int kc = 0; kc < 2; ++kc) {
            bf16x8 ah[4], al[4], bh2[2], bl2[2];
            #pragma unroll
            for (int mi = 0; mi < 4; ++mi) {
                ah[mi] = *(const bf16x8*)(smem +        afo[mi] + g16[kc]);
                al[mi] = *(const bf16x8*)(smem + 4096 + afo[mi] + g16[kc]);
            }
            #pragma unroll
            for (int ni = 0; ni < 2; ++ni) {
                bh2[ni] = *(const bf16x8*)(smem +  8192 + bfo[ni] + g16[kc]);
                bl2[ni] = *(const bf16x8*)(smem + 16384 + bfo[ni] + g16[kc]);
            }
            #pragma unroll
            for (int mi = 0; mi < 4; ++mi)
                #pragma unroll
                for (int ni = 0; ni < 2; ++ni) {
                    acc[mi][ni] = __builtin_amdgcn_mfma_f32_16x16x32_bf16(
                        ah[mi], bh2[ni], acc[mi][ni], 0, 0, 0);
                    acc[mi][ni] = __builtin_amdgcn_mfma_f32_16x16x32_bf16(
                        ah[mi], bl2[ni], acc[mi][ni], 0, 0, 0);
                    acc[mi][ni] = __builtin_amdgcn_mfma_f32_16x16x32_bf16(
                        al[mi], bh2[ni], acc[mi][ni], 0, 0, 0);
                }
        }
    }

    // --- epilogue: D row = (lane>>4)*4 + r, col = lane&15 (m89-verified) ---
    #pragma unroll
    for (int ni = 0; ni < 2; ++ni) {
        const int col = col0 + wv * 32 + ni * 16 + (lane & 15);
        const float bval = ldin(bias, col, F);
        #pragma unroll
        for (int mi = 0; mi < 4; ++mi) {
            const int row0 = m0 + mi * 16 + (lane >> 4) * 4;
            #pragma unroll
            for (int r = 0; r < 4; ++r) {
                const int row = row0 + r;
                float v = acc[mi][ni][r] + bval;
                if (MODE == 1) v += ldin(xres, row * HIDC + col, F);
                Out[row * HIDC + col] = v;
            }
        }
    }
}

// ---------------- K2: rfft(64) + amplitude normalization ----------------
__global__ __launch_bounds__(64) void spectral_kernel(
    const float* __restrict__ Q, const float* __restrict__ K,
    float* __restrict__ Qn, float* __restrict__ Kn)
{
    __shared__ float qv[64];
    __shared__ float tc[64], tsn[64];
    const int unit = blockIdx.x;          // s*16 + h
    const int sel  = blockIdx.y;          // 0: Q, 1: K
    const int s = unit >> 4, h = unit & 15;
    const float* src = sel ? K : Q;
    float* dst = sel ? Kn : Qn;
    const int t = threadIdx.x;

    qv[t] = src[s * HIDC + h * HDIM + t];
    float sv, cv;
    sincosf((float)t * (6.283185307179586f / 64.0f), &sv, &cv);
    tc[t] = cv; tsn[t] = sv;
    __syncthreads();

    if (t < NFREQ) {
        float re = 0.0f, im = 0.0f;
        #pragma unroll
        for (int k = 0; k < 64; ++k) {
            const int idx = (t * k) & 63;
            re = fmaf(qv[k], tc[idx], re);
            im = fmaf(qv[k], -tsn[idx], im);
        }
        const float a  = sqrtf(re * re + im * im);
        const float sc = (a > 0.0f) ? rsqrtf(a) : 0.0f;
        const int base = (h * SEQ + s) * NF2V;
        dst[base + t]         = re * sc;
        dst[base + NFREQ + t] = im * sc;
    }
}

// ---------------- K3: attention ----------------
__global__ __launch_bounds__(256) void attn_kernel(
    const float* __restrict__ Qn, const float* __restrict__ Kn,
    const float* __restrict__ V, const int* __restrict__ mask,
    const void* __restrict__ temp_p, float* __restrict__ ctx,
    const int* __restrict__ flagp)
{
    __shared__ float qn[8][NF2V];
    __shared__ float sc[8][SEQ];
    __shared__ float kt[64 * 67];
    __shared__ float red[4][8][64];
    __shared__ float rowsum[8];

    const int F   = *flagp;
    const int tid = threadIdx.x;
    const int h   = blockIdx.y;
    const int q0  = blockIdx.x * 8;
    const float temp = ldin(temp_p, 0, F);

    for (int idx = tid; idx < 8 * NF2V; idx += 256) {
        const int r = idx / NF2V, f = idx % NF2V;
        qn[r][f] = Qn[(h * SEQ + q0 + r) * NF2V + f];
    }
    __syncthreads();

    for (int kt0 = 0; kt0 < SEQ; kt0 += 64) {
        for (int idx = tid; idx < 64 * NF2V; idx += 256) {
            const int kk = idx / NF2V, f = idx % NF2V;
            kt[kk * 67 + f] = Kn[(h * SEQ + kt0 + kk) * NF2V + f];
        }
        __syncthreads();
        #pragma unroll
        for (int it = 0; it < 2; ++it) {
            const int item = tid + it * 256;
            const int r = item >> 6, kk = item & 63;
            float d = 0.0f;
            #pragma unroll
            for (int f = 0; f < NF2V; ++f) d = fmaf(qn[r][f], kt[kk * 67 + f], d);
            const int kabs = kt0 + kk;
            float sco = d * temp;
            if (mask[kabs] == 0) sco = -1e9f;
            sc[r][kabs] = sco;
        }
        __syncthreads();
    }

    const int w = tid >> 6, lane = tid & 63;
    for (int rr = 0; rr < 2; ++rr) {
        const int r = w * 2 + rr;
        float m = -1e30f;
        for (int k = lane; k < SEQ; k += 64) m = fmaxf(m, sc[r][k]);
        #pragma unroll
        for (int off = 32; off > 0; off >>= 1) m = fmaxf(m, __shfl_xor(m, off, 64));
        float sum = 0.0f;
        for (int k = lane; k < SEQ; k += 64) {
            const float e = __expf(sc[r][k] - m);
            sc[r][k] = e;
            sum += e;
        }
        #pragma unroll
        for (int off = 32; off > 0; off >>= 1) sum += __shfl_xor(sum, off, 64);
        if (lane == 0) rowsum[r] = sum;
    }
    __syncthreads();

    {
        const int d = tid & 63, c = tid >> 6;
        float acc[8] = {};
        const float* vcol = V + h * HDIM + d;
        for (int k = c * 128; k < c * 128 + 128; ++k) {
            const float v = vcol[k * HIDC];
            #pragma unroll
            for (int r = 0; r < 8; ++r) acc[r] = fmaf(sc[r][k], v, acc[r]);
        }
        #pragma unroll
        for (int r = 0; r < 8; ++r) red[c][r][d] = acc[r];
    }
    __syncthreads();
    #pragma unroll
    for (int p = 0; p < 2; ++p) {
        const int item = tid + p * 256;
        const int r = item >> 6, dd = item & 63;
        const float sum4 = red[0][r][dd] + red[1][r][dd] + red[2][r][dd] + red[3][r][dd];
        ctx[(q0 + r) * HIDC + h * HDIM + dd] = sum4 / rowsum[r];
    }
}

// ---------------- K5: LayerNorm -> out ----------------
__global__ __launch_bounds__(256) void ln_kernel(
    const float* __restrict__ Y, const void* __restrict__ gamma,
    const void* __restrict__ beta, void* __restrict__ out,
    const int* __restrict__ flagp)
{
    const int F = *flagp;
    const int row = blockIdx.x, tid = threadIdx.x;
    float v[4];
    float s = 0.0f, s2 = 0.0f;
    #pragma unroll
    for (int j = 0; j < 4; ++j) {
        v[j] = Y[row * HIDC + tid + j * 256];
        s += v[j]; s2 += v[j] * v[j];
    }
    #pragma unroll
    for (int off = 32; off > 0; off >>= 1) {
        s  += __shfl_xor(s, off, 64);
        s2 += __shfl_xor(s2, off, 64);
    }
    __shared__ float wred[4][2];
    const int w = tid >> 6;
    if ((tid & 63) == 0) { wred[w][0] = s; wred[w][1] = s2; }
    __syncthreads();
    s  = wred[0][0] + wred[1][0] + wred[2][0] + wred[3][0];
    s2 = wred[0][1] + wred[1][1] + wred[2][1] + wred[3][1];
    const float mu   = s / (float)HIDC;
    const float var  = s2 / (float)HIDC - mu * mu;
    const float rstd = rsqrtf(var + 1e-5f);
    #pragma unroll
    for (int j = 0; j < 4; ++j) {
        const int c = tid + j * 256;
        const float g = ldin(gamma, c, F), b = ldin(beta, c, F);
        const float r = (v[j] - mu) * rstd * g + b;
        if (F) ((float*)out)[row * HIDC + c] = r;
        else   ((__hip_bfloat16*)out)[row * HIDC + c] = __float2bfloat16(r);
    }
}

extern "C" void kernel_launch(void* const* d_in, const int* in_sizes, int n_in,
                              void* d_out, int out_size, void* d_ws, size_t ws_size,
                              hipStream_t stream) {
    const void* x    = d_in[0];
    const int*  mask = (const int*)d_in[1];
    const void* Wq   = d_in[2];
    const void* bq   = d_in[3];
    const void* Wk   = d_in[4];
    const void* bk   = d_in[5];
    const void* Wv   = d_in[6];
    const void* bv   = d_in[7];
    const void* Wo   = d_in[8];
    const void* bo   = d_in[9];
    const void* temp = d_in[10];
    const void* gam  = d_in[11];
    const void* bet  = d_in[12];

    float* ws   = (float*)d_ws;
    int*   flag = (int*)ws;                  // 16B reserved
    float* Q    = ws + 4;                    // 512*1024 f32
    float* K    = Q   + SEQ * HIDC;
    float* V    = K   + SEQ * HIDC;
    float* Qn   = V   + SEQ * HIDC;          // 16*512*66 f32
    float* Kn   = Qn  + NH * SEQ * NF2V;
    float* ctx  = Kn  + NH * SEQ * NF2V;     // 512*1024 f32
    float* Y    = ctx + SEQ * HIDC;          // 512*1024 f32
    u16*   xhi  = (u16*)(Y + SEQ * HIDC);    // 512*1024 bf16 each
    u16*   xlo  = xhi + SEQ * HIDC;
    u16*   chi  = xlo + SEQ * HIDC;
    u16*   clo  = chi + SEQ * HIDC;
    u16*   Wqh  = clo + SEQ * HIDC;          // 8 x 1024*1024 bf16
    u16*   Wql  = Wqh + HIDC * HIDC;
    u16*   Wkh  = Wql + HIDC * HIDC;
    u16*   Wkl  = Wkh + HIDC * HIDC;
    u16*   Wvh  = Wkl + HIDC * HIDC;
    u16*   Wvl  = Wvh + HIDC * HIDC;
    u16*   Woh  = Wvl + HIDC * HIDC;
    u16*   Wol  = Woh + HIDC * HIDC;

    sniff_kernel<<<1, 256, 0, stream>>>(Wq, flag);

    // prep: W transpose+split, x split
    wsplit_kernel<<<dim3(16, 16, 4), 256, 0, stream>>>(
        Wq, Wk, Wv, Wo, Wqh, Wql, Wkh, Wkl, Wvh, Wvl, Woh, Wol, flag);
    xsplit_kernel<<<512, 256, 0, stream>>>(x, xhi, xlo, flag, 0);

    // QKV projection (split-bf16 MFMA, fp32 out)
    mfma3_gemm_kernel<0><<<dim3(24, 8), 256, 0, stream>>>(
        xhi, xlo, Wqh, Wql, Wkh, Wkl, Wvh, Wvl,
        bq, bk, bv, nullptr, Q, K, V, flag);

    spectral_kernel<<<dim3(SEQ * NH, 2), 64, 0, stream>>>(Q, K, Qn, Kn);
    attn_kernel<<<dim3(SEQ / 8, NH), 256, 0, stream>>>(Qn, Kn, V, mask, temp, ctx, flag);

    // O-projection: split ctx, then MFMA with bias+residual
    xsplit_kernel<<<512, 256, 0, stream>>>(ctx, chi, clo, flag, 1);
    mfma3_gemm_kernel<1><<<dim3(8, 8), 256, 0, stream>>>(
        chi, clo, Woh, Wol, nullptr, nullptr, nullptr, nullptr,
        bo, nullptr, nullptr, x, Y, nullptr, nullptr, flag);

    ln_kernel<<<SEQ, 256, 0, stream>>>(Y, gam, bet, d_out, flag);
}

// Round 3
// 229.782 us; speedup vs baseline: 2.0829x; 1.4031x over previous
//
#include <hip/hip_runtime.h>
#include <hip/hip_bf16.h>
#include <math.h>

constexpr int SEQ   = 512;
constexpr int HIDC  = 1024;
constexpr int NH    = 16;
constexpr int HDIM  = 64;
constexpr int NFREQ = 33;   // rfft bins for n=64
constexpr int NF2V  = 66;   // packed (Re|Im) length

typedef unsigned short u16;
typedef __bf16 bf16x8 __attribute__((ext_vector_type(8)));
typedef float  f32x4  __attribute__((ext_vector_type(4)));

typedef __attribute__((address_space(3))) void       as3_void;
typedef __attribute__((address_space(1))) const void as1_void;

// async global->LDS, 16B per lane; LDS dest = uniform base + lane*16
__device__ __forceinline__ void gload16(const u16* g, u16* l) {
    __builtin_amdgcn_global_load_lds((as1_void*)g, (as3_void*)l, 16, 0, 0);
}

// dtype-agnostic input load: f32 ? float : bf16
__device__ __forceinline__ float ldin(const void* p, int i, int f32) {
    if (f32) return ((const float*)p)[i];
    return __bfloat162float(((const __hip_bfloat16*)p)[i]);
}

__device__ __forceinline__ u16 f2b(float f) {   // RNE fp32 -> bf16 bits
    unsigned int u = __builtin_bit_cast(unsigned int, f);
    u += 0x7fffu + ((u >> 16) & 1u);
    return (u16)(u >> 16);
}
__device__ __forceinline__ float b2f(u16 b) {
    return __builtin_bit_cast(float, (unsigned int)b << 16);
}
// fp32 -> (hi, lo) bf16 pair; hi + lo ~ f to ~16 mantissa bits
__device__ __forceinline__ void split2(float f, u16& hi, u16& lo) {
    hi = f2b(f);
    lo = f2b(f - b2f(hi));
}

// ---------------- K0: dtype sniff ----------------
__global__ void sniff_kernel(const void* w, int* flag) {
    __shared__ int cnt;
    if (threadIdx.x == 0) cnt = 0;
    __syncthreads();
    const unsigned short* h = (const unsigned short*)w;
    int bad = 0;
    for (int i = threadIdx.x; i < 512; i += 256) {
        const unsigned short v = h[i];
        const int ex = (v >> 7) & 0xFF;   // bf16 exponent field
        if (ex >= 134) bad++;             // |x| >= 128 (or inf/nan)
    }
    atomicAdd(&cnt, bad);
    __syncthreads();
    if (threadIdx.x == 0) flag[0] = (cnt > 32) ? 1 : 0;
}

// ---------------- K1a: W transpose + hi/lo split ----------------
// W[k][n] (dtype per flag) -> Wthi[n][k], Wtlo[n][k] (bf16 bits)
__global__ __launch_bounds__(256) void wsplit_kernel(
    const void* __restrict__ W0, const void* __restrict__ W1,
    const void* __restrict__ W2, const void* __restrict__ W3,
    u16* __restrict__ H0, u16* __restrict__ L0,
    u16* __restrict__ H1, u16* __restrict__ L1,
    u16* __restrict__ H2, u16* __restrict__ L2,
    u16* __restrict__ H3, u16* __restrict__ L3,
    const int* __restrict__ flagp)
{
    __shared__ float t[64][65];
    const int F  = *flagp;
    const int mz = blockIdx.z;
    const void* W = (mz == 0) ? W0 : (mz == 1) ? W1 : (mz == 2) ? W2 : W3;
    u16* H = (mz == 0) ? H0 : (mz == 1) ? H1 : (mz == 2) ? H2 : H3;
    u16* L = (mz == 0) ? L0 : (mz == 1) ? L1 : (mz == 2) ? L2 : L3;
    const int n0 = blockIdx.x * 64, k0 = blockIdx.y * 64;
    const int tid = threadIdx.x;

    #pragma unroll
    for (int i = 0; i < 4; ++i) {
        const int item = i * 256 + tid;
        const int r = item >> 4, c4 = (item & 15) * 4;
        if (F) {
            const float4 v = *(const float4*)((const float*)W + (k0 + r) * HIDC + n0 + c4);
            t[r][c4 + 0] = v.x; t[r][c4 + 1] = v.y; t[r][c4 + 2] = v.z; t[r][c4 + 3] = v.w;
        } else {
            #pragma unroll
            for (int j = 0; j < 4; ++j)
                t[r][c4 + j] = ldin(W, (k0 + r) * HIDC + n0 + c4 + j, 0);
        }
    }
    __syncthreads();
    #pragma unroll
    for (int i = 0; i < 4; ++i) {
        const int item = i * 256 + tid;
        const int r = item >> 4, c4 = (item & 15) * 4;   // r: n-offset, c4: k-offset
        ushort4 oh, ol;
        u16 h, l;
        split2(t[c4 + 0][r], h, l); oh.x = h; ol.x = l;
        split2(t[c4 + 1][r], h, l); oh.y = h; ol.y = l;
        split2(t[c4 + 2][r], h, l); oh.z = h; ol.z = l;
        split2(t[c4 + 3][r], h, l); oh.w = h; ol.w = l;
        *(ushort4*)&H[(n0 + r) * HIDC + k0 + c4] = oh;
        *(ushort4*)&L[(n0 + r) * HIDC + k0 + c4] = ol;
    }
}

// ---------------- K1b: activation hi/lo split (x or ctx) ----------------
__global__ __launch_bounds__(256) void xsplit_kernel(
    const void* __restrict__ src, u16* __restrict__ hi, u16* __restrict__ lo,
    const int* __restrict__ flagp, int force_f32)
{
    const int F = force_f32 ? 1 : *flagp;
    const int i = blockIdx.x * 1024 + threadIdx.x * 4;
    float v[4];
    if (F) {
        const float4 f = *(const float4*)((const float*)src + i);
        v[0] = f.x; v[1] = f.y; v[2] = f.z; v[3] = f.w;
    } else {
        #pragma unroll
        for (int j = 0; j < 4; ++j) v[j] = ldin(src, i + j, 0);
    }
    ushort4 oh, ol;
    u16 h, l;
    split2(v[0], h, l); oh.x = h; ol.x = l;
    split2(v[1], h, l); oh.y = h; ol.y = l;
    split2(v[2], h, l); oh.z = h; ol.z = l;
    split2(v[3], h, l); oh.w = h; ol.w = l;
    *(ushort4*)&hi[i] = oh;
    *(ushort4*)&lo[i] = ol;
}

// ---------------- K1c: 3-term split-bf16 MFMA GEMM ----------------
// C = (Ahi+Alo) @ (Bhi+Blo)^T ~= Ahi@Bhi + Ahi@Blo + Alo@Bhi  (fp32 acc)
// Staging via global_load_lds (zero VGPR staging), double-buffered LDS,
// 2-phase pipeline: stage(t+1) issued before compute(t), drained at barrier.
// LDS buffer layout (u16 units): AH @0, AL @4096, BH @8192, BL @16384.
// Swizzle: LDS[row][g] holds G[row][g ^ (row&7)] (16B granules), achieved by
// pre-swizzling the per-lane GLOBAL source (linear LDS dest, rule #21).
// MODE 0: QKV (grid.x = 24 spans Q|K|V col-blocks), out = acc + bias
// MODE 1: O-proj (grid.x = 8), out = acc + bias + residual(x)
template <int MODE>
__global__ __launch_bounds__(256) void mfma3_gemm_kernel(
    const u16* __restrict__ Ahi, const u16* __restrict__ Alo,
    const u16* __restrict__ B0h, const u16* __restrict__ B0l,
    const u16* __restrict__ B1h, const u16* __restrict__ B1l,
    const u16* __restrict__ B2h, const u16* __restrict__ B2l,
    const void* __restrict__ b0, const void* __restrict__ b1, const void* __restrict__ b2,
    const void* __restrict__ xres,
    float* __restrict__ O0, float* __restrict__ O1, float* __restrict__ O2,
    const int* __restrict__ flagp)
{
    __shared__ __align__(16) u16 smem[2 * 24576];   // 96 KB double buffer
    const int F    = *flagp;
    const int tid  = threadIdx.x;
    const int lane = tid & 63, wv = tid >> 6;
    const int m0 = blockIdx.y * 64;
    const int n0 = blockIdx.x * 128;

    const u16 *Bh, *Bl; const void* bias; float* Out; int col0;
    if (MODE == 0) {
        const int mat = n0 >> 10;
        col0 = n0 & 1023;
        Bh   = (mat == 0) ? B0h : (mat == 1) ? B1h : B2h;
        Bl   = (mat == 0) ? B0l : (mat == 1) ? B1l : B2l;
        bias = (mat == 0) ? b0  : (mat == 1) ? b1  : b2;
        Out  = (mat == 0) ? O0  : (mat == 1) ? O1  : O2;
    } else {
        col0 = n0; Bh = B0h; Bl = B0l; bias = b0; Out = O0;
    }

    // --- staging geometry: chunk = 8 rows x 64 k = 1KB = one wave gload16 ---
    // AH/AL: 8 chunks each (2/wave); BH/BL: 16 chunks each (4/wave)
    const int rsub = lane >> 3;                        // row within chunk
    const int gsw  = ((lane & 7) ^ rsub) * 8;          // swizzled src granule (u16)
    const u16* pAh[2]; const u16* pAl[2];
    const u16* pBh[4]; const u16* pBl[4];
    int dA[2], dB[4];                                  // LDS chunk offsets (u16)
    #pragma unroll
    for (int j = 0; j < 2; ++j) {
        const int c = wv * 2 + j;
        pAh[j] = Ahi + (m0 + c * 8 + rsub) * HIDC + gsw;
        pAl[j] = Alo + (m0 + c * 8 + rsub) * HIDC + gsw;
        dA[j]  = c * 512;
    }
    #pragma unroll
    for (int j = 0; j < 4; ++j) {
        const int c = wv * 4 + j;
        pBh[j] = Bh + (col0 + c * 8 + rsub) * HIDC + gsw;
        pBl[j] = Bl + (col0 + c * 8 + rsub) * HIDC + gsw;
        dB[j]  = c * 512;
    }

    // --- fragment read offsets (swizzle-consistent) ---
    int g16[2];
    #pragma unroll
    for (int kc = 0; kc < 2; ++kc) g16[kc] = (((kc * 4) + (lane >> 4)) ^ (lane & 7)) * 8;
    int afo[4], bfo[2];
    #pragma unroll
    for (int mi = 0; mi < 4; ++mi) afo[mi] = (mi * 16 + (lane & 15)) * 64;
    #pragma unroll
    for (int ni = 0; ni < 2; ++ni) bfo[ni] = (wv * 32 + ni * 16 + (lane & 15)) * 64;

    f32x4 zero = {0.f, 0.f, 0.f, 0.f};
    f32x4 acc[4][2];
    #pragma unroll
    for (int mi = 0; mi < 4; ++mi)
        #pragma unroll
        for (int ni = 0; ni < 2; ++ni) acc[mi][ni] = zero;

    // prologue: stage K-step 0 into buffer 0
    #pragma unroll
    for (int j = 0; j < 2; ++j) {
        gload16(pAh[j], smem + dA[j]);
        gload16(pAl[j], smem + 4096 + dA[j]);
    }
    #pragma unroll
    for (int j = 0; j < 4; ++j) {
        gload16(pBh[j], smem + 8192  + dB[j]);
        gload16(pBl[j], smem + 16384 + dB[j]);
    }
    __syncthreads();   // drains vmcnt -> buffer 0 ready

    for (int t = 0; t < 16; ++t) {
        const int bo = (t & 1) * 24576;
        if (t < 15) {
            const int bn = 24576 - bo;
            const int k  = (t + 1) * 64;
            #pragma unroll
            for (int j = 0; j < 2; ++j) {
                gload16(pAh[j] + k, smem + bn + dA[j]);
                gload16(pAl[j] + k, smem + bn + 4096 + dA[j]);
            }
            #pragma unroll
            for (int j = 0; j < 4; ++j) {
                gload16(pBh[j] + k, smem + bn + 8192  + dB[j]);
                gload16(pBl[j] + k, smem + bn + 16384 + dB[j]);
            }
        }
        #pragma unroll
        for (int kc = 0; kc < 2; ++kc) {
            bf16x8 ah[4], al[4], bh2[2], bl2[2];
            #pragma unroll
            for (int mi = 0; mi < 4; ++mi) {
                ah[mi] = *(const bf16x8*)(smem + bo +        afo[mi] + g16[kc]);
                al[mi] = *(const bf16x8*)(smem + bo + 4096 + afo[mi] + g16[kc]);
            }
            #pragma unroll
            for (int ni = 0; ni < 2; ++ni) {
                bh2[ni] = *(const bf16x8*)(smem + bo +  8192 + bfo[ni] + g16[kc]);
                bl2[ni] = *(const bf16x8*)(smem + bo + 16384 + bfo[ni] + g16[kc]);
            }
            #pragma unroll
            for (int mi = 0; mi < 4; ++mi)
                #pragma unroll
                for (int ni = 0; ni < 2; ++ni) {
                    acc[mi][ni] = __builtin_amdgcn_mfma_f32_16x16x32_bf16(
                        ah[mi], bh2[ni], acc[mi][ni], 0, 0, 0);
                    acc[mi][ni] = __builtin_amdgcn_mfma_f32_16x16x32_bf16(
                        ah[mi], bl2[ni], acc[mi][ni], 0, 0, 0);
                    acc[mi][ni] = __builtin_amdgcn_mfma_f32_16x16x32_bf16(
                        al[mi], bh2[ni], acc[mi][ni], 0, 0, 0);
                }
        }
        __syncthreads();   // drains stage(t+1) loads + publishes buffer swap
    }

    // --- epilogue: D row = (lane>>4)*4 + r, col = lane&15 (m89-verified) ---
    #pragma unroll
    for (int ni = 0; ni < 2; ++ni) {
        const int col = col0 + wv * 32 + ni * 16 + (lane & 15);
        const float bval = ldin(bias, col, F);
        #pragma unroll
        for (int mi = 0; mi < 4; ++mi) {
            const int row0 = m0 + mi * 16 + (lane >> 4) * 4;
            #pragma unroll
            for (int r = 0; r < 4; ++r) {
                const int row = row0 + r;
                float v = acc[mi][ni][r] + bval;
                if (MODE == 1) v += ldin(xres, row * HIDC + col, F);
                Out[row * HIDC + col] = v;
            }
        }
    }
}

// ---------------- K2: rfft(64) + amplitude normalization ----------------
__global__ __launch_bounds__(64) void spectral_kernel(
    const float* __restrict__ Q, const float* __restrict__ K,
    float* __restrict__ Qn, float* __restrict__ Kn)
{
    __shared__ float qv[64];
    __shared__ float tc[64], tsn[64];
    const int unit = blockIdx.x;          // s*16 + h
    const int sel  = blockIdx.y;          // 0: Q, 1: K
    const int s = unit >> 4, h = unit & 15;
    const float* src = sel ? K : Q;
    float* dst = sel ? Kn : Qn;
    const int t = threadIdx.x;

    qv[t] = src[s * HIDC + h * HDIM + t];
    float sv, cv;
    sincosf((float)t * (6.283185307179586f / 64.0f), &sv, &cv);
    tc[t] = cv; tsn[t] = sv;
    __syncthreads();

    if (t < NFREQ) {
        float re = 0.0f, im = 0.0f;
        #pragma unroll
        for (int k = 0; k < 64; ++k) {
            const int idx = (t * k) & 63;
            re = fmaf(qv[k], tc[idx], re);
            im = fmaf(qv[k], -tsn[idx], im);
        }
        const float a  = sqrtf(re * re + im * im);
        const float sc = (a > 0.0f) ? rsqrtf(a) : 0.0f;
        const int base = (h * SEQ + s) * NF2V;
        dst[base + t]         = re * sc;
        dst[base + NFREQ + t] = im * sc;
    }
}

// ---------------- K3: attention ----------------
__global__ __launch_bounds__(256) void attn_kernel(
    const float* __restrict__ Qn, const float* __restrict__ Kn,
    const float* __restrict__ V, const int* __restrict__ mask,
    const void* __restrict__ temp_p, float* __restrict__ ctx,
    const int* __restrict__ flagp)
{
    __shared__ float qn[8][NF2V];
    __shared__ float sc[8][SEQ];
    __shared__ float kt[64 * 67];
    __shared__ float red[4][8][64];
    __shared__ float rowsum[8];

    const int F   = *flagp;
    const int tid = threadIdx.x;
    const int h   = blockIdx.y;
    const int q0  = blockIdx.x * 8;
    const float temp = ldin(temp_p, 0, F);

    for (int idx = tid; idx < 8 * NF2V; idx += 256) {
        const int r = idx / NF2V, f = idx % NF2V;
        qn[r][f] = Qn[(h * SEQ + q0 + r) * NF2V + f];
    }
    __syncthreads();

    for (int kt0 = 0; kt0 < SEQ; kt0 += 64) {
        for (int idx = tid; idx < 64 * NF2V; idx += 256) {
            const int kk = idx / NF2V, f = idx % NF2V;
            kt[kk * 67 + f] = Kn[(h * SEQ + kt0 + kk) * NF2V + f];
        }
        __syncthreads();
        #pragma unroll
        for (int it = 0; it < 2; ++it) {
            const int item = tid + it * 256;
            const int r = item >> 6, kk = item & 63;
            float d = 0.0f;
            #pragma unroll
            for (int f = 0; f < NF2V; ++f) d = fmaf(qn[r][f], kt[kk * 67 + f], d);
            const int kabs = kt0 + kk;
            float sco = d * temp;
            if (mask[kabs] == 0) sco = -1e9f;
            sc[r][kabs] = sco;
        }
        __syncthreads();
    }

    const int w = tid >> 6, lane = tid & 63;
    for (int rr = 0; rr < 2; ++rr) {
        const int r = w * 2 + rr;
        float m = -1e30f;
        for (int k = lane; k < SEQ; k += 64) m = fmaxf(m, sc[r][k]);
        #pragma unroll
        for (int off = 32; off > 0; off >>= 1) m = fmaxf(m, __shfl_xor(m, off, 64));
        float sum = 0.0f;
        for (int k = lane; k < SEQ; k += 64) {
            const float e = __expf(sc[r][k] - m);
            sc[r][k] = e;
            sum += e;
        }
        #pragma unroll
        for (int off = 32; off > 0; off >>= 1) sum += __shfl_xor(sum, off, 64);
        if (lane == 0) rowsum[r] = sum;
    }
    __syncthreads();

    {
        const int d = tid & 63, c = tid >> 6;
        float acc[8] = {};
        const float* vcol = V + h * HDIM + d;
        for (int k = c * 128; k < c * 128 + 128; ++k) {
            const float v = vcol[k * HIDC];
            #pragma unroll
            for (int r = 0; r < 8; ++r) acc[r] = fmaf(sc[r][k], v, acc[r]);
        }
        #pragma unroll
        for (int r = 0; r < 8; ++r) red[c][r][d] = acc[r];
    }
    __syncthreads();
    #pragma unroll
    for (int p = 0; p < 2; ++p) {
        const int item = tid + p * 256;
        const int r = item >> 6, dd = item & 63;
        const float sum4 = red[0][r][dd] + red[1][r][dd] + red[2][r][dd] + red[3][r][dd];
        ctx[(q0 + r) * HIDC + h * HDIM + dd] = sum4 / rowsum[r];
    }
}

// ---------------- K5: LayerNorm -> out ----------------
__global__ __launch_bounds__(256) void ln_kernel(
    const float* __restrict__ Y, const void* __restrict__ gamma,
    const void* __restrict__ beta, void* __restrict__ out,
    const int* __restrict__ flagp)
{
    const int F = *flagp;
    const int row = blockIdx.x, tid = threadIdx.x;
    float v[4];
    float s = 0.0f, s2 = 0.0f;
    #pragma unroll
    for (int j = 0; j < 4; ++j) {
        v[j] = Y[row * HIDC + tid + j * 256];
        s += v[j]; s2 += v[j] * v[j];
    }
    #pragma unroll
    for (int off = 32; off > 0; off >>= 1) {
        s  += __shfl_xor(s, off, 64);
        s2 += __shfl_xor(s2, off, 64);
    }
    __shared__ float wred[4][2];
    const int w = tid >> 6;
    if ((tid & 63) == 0) { wred[w][0] = s; wred[w][1] = s2; }
    __syncthreads();
    s  = wred[0][0] + wred[1][0] + wred[2][0] + wred[3][0];
    s2 = wred[0][1] + wred[1][1] + wred[2][1] + wred[3][1];
    const float mu   = s / (float)HIDC;
    const float var  = s2 / (float)HIDC - mu * mu;
    const float rstd = rsqrtf(var + 1e-5f);
    #pragma unroll
    for (int j = 0; j < 4; ++j) {
        const int c = tid + j * 256;
        const float g = ldin(gamma, c, F), b = ldin(beta, c, F);
        const float r = (v[j] - mu) * rstd * g + b;
        if (F) ((float*)out)[row * HIDC + c] = r;
        else   ((__hip_bfloat16*)out)[row * HIDC + c] = __float2bfloat16(r);
    }
}

extern "C" void kernel_launch(void* const* d_in, const int* in_sizes, int n_in,
                              void* d_out, int out_size, void* d_ws, size_t ws_size,
                              hipStream_t stream) {
    const void* x    = d_in[0];
    const int*  mask = (const int*)d_in[1];
    const void* Wq   = d_in[2];
    const void* bq   = d_in[3];
    const void* Wk   = d_in[4];
    const void* bk   = d_in[5];
    const void* Wv   = d_in[6];
    const void* bv   = d_in[7];
    const void* Wo   = d_in[8];
    const void* bo   = d_in[9];
    const void* temp = d_in[10];
    const void* gam  = d_in[11];
    const void* bet  = d_in[12];

    float* ws   = (float*)d_ws;
    int*   flag = (int*)ws;                  // 16B reserved
    float* Q    = ws + 4;                    // 512*1024 f32
    float* K    = Q   + SEQ * HIDC;
    float* V    = K   + SEQ * HIDC;
    float* Qn   = V   + SEQ * HIDC;          // 16*512*66 f32
    float* Kn   = Qn  + NH * SEQ * NF2V;
    float* ctx  = Kn  + NH * SEQ * NF2V;     // 512*1024 f32
    float* Y    = ctx + SEQ * HIDC;          // 512*1024 f32
    u16*   xhi  = (u16*)(Y + SEQ * HIDC);    // 512*1024 bf16 each
    u16*   xlo  = xhi + SEQ * HIDC;
    u16*   chi  = xlo + SEQ * HIDC;
    u16*   clo  = chi + SEQ * HIDC;
    u16*   Wqh  = clo + SEQ * HIDC;          // 8 x 1024*1024 bf16
    u16*   Wql  = Wqh + HIDC * HIDC;
    u16*   Wkh  = Wql + HIDC * HIDC;
    u16*   Wkl  = Wkh + HIDC * HIDC;
    u16*   Wvh  = Wkl + HIDC * HIDC;
    u16*   Wvl  = Wvh + HIDC * HIDC;
    u16*   Woh  = Wvl + HIDC * HIDC;
    u16*   Wol  = Woh + HIDC * HIDC;

    sniff_kernel<<<1, 256, 0, stream>>>(Wq, flag);

    // prep: W transpose+split, x split
    wsplit_kernel<<<dim3(16, 16, 4), 256, 0, stream>>>(
        Wq, Wk, Wv, Wo, Wqh, Wql, Wkh, Wkl, Wvh, Wvl, Woh, Wol, flag);
    xsplit_kernel<<<512, 256, 0, stream>>>(x, xhi, xlo, flag, 0);

    // QKV projection (split-bf16 MFMA, fp32 out)
    mfma3_gemm_kernel<0><<<dim3(24, 8), 256, 0, stream>>>(
        xhi, xlo, Wqh, Wql, Wkh, Wkl, Wvh, Wvl,
        bq, bk, bv, nullptr, Q, K, V, flag);

    spectral_kernel<<<dim3(SEQ * NH, 2), 64, 0, stream>>>(Q, K, Qn, Kn);
    attn_kernel<<<dim3(SEQ / 8, NH), 256, 0, stream>>>(Qn, Kn, V, mask, temp, ctx, flag);

    // O-projection: split ctx, then MFMA with bias+residual
    xsplit_kernel<<<512, 256, 0, stream>>>(ctx, chi, clo, flag, 1);
    mfma3_gemm_kernel<1><<<dim3(8, 8), 256, 0, stream>>>(
        chi, clo, Woh, Wol, nullptr, nullptr, nullptr, nullptr,
        bo, nullptr, nullptr, x, Y, nullptr, nullptr, flag);

    ln_kernel<<<SEQ, 256, 0, stream>>>(Y, gam, bet, d_out, flag);
}

// Round 4
// 186.715 us; speedup vs baseline: 2.5633x; 1.2307x over previous
//
#include <hip/hip_runtime.h>
#include <hip/hip_bf16.h>
#include <math.h>

constexpr int SEQ   = 512;
constexpr int HIDC  = 1024;
constexpr int NH    = 16;
constexpr int HDIM  = 64;
constexpr int NFREQ = 33;   // rfft bins for n=64
constexpr int NFP   = 128;  // padded packed spectral length (66 -> 128, zero pad)

typedef unsigned short u16;
typedef __bf16 bf16x8 __attribute__((ext_vector_type(8)));
typedef float  f32x4  __attribute__((ext_vector_type(4)));

typedef __attribute__((address_space(3))) void       as3_void;
typedef __attribute__((address_space(1))) const void as1_void;

// async global->LDS, 16B per lane; LDS dest = wave-uniform base + lane*16
__device__ __forceinline__ void gload16(const u16* g, u16* l) {
    __builtin_amdgcn_global_load_lds((as1_void*)g, (as3_void*)l, 16, 0, 0);
}

// dtype-agnostic input load: f32 ? float : bf16
__device__ __forceinline__ float ldin(const void* p, int i, int f32) {
    if (f32) return ((const float*)p)[i];
    return __bfloat162float(((const __hip_bfloat16*)p)[i]);
}

__device__ __forceinline__ u16 f2b(float f) {   // RNE fp32 -> bf16 bits
    unsigned int u = __builtin_bit_cast(unsigned int, f);
    u += 0x7fffu + ((u >> 16) & 1u);
    return (u16)(u >> 16);
}
__device__ __forceinline__ float b2f(u16 b) {
    return __builtin_bit_cast(float, (unsigned int)b << 16);
}
// fp32 -> (hi, lo) bf16 pair; hi + lo ~ f to ~16 mantissa bits
__device__ __forceinline__ void split2(float f, u16& hi, u16& lo) {
    hi = f2b(f);
    lo = f2b(f - b2f(hi));
}

// ---------------- K0: dtype sniff ----------------
__global__ void sniff_kernel(const void* w, int* flag) {
    __shared__ int cnt;
    if (threadIdx.x == 0) cnt = 0;
    __syncthreads();
    const unsigned short* h = (const unsigned short*)w;
    int bad = 0;
    for (int i = threadIdx.x; i < 512; i += 256) {
        const unsigned short v = h[i];
        const int ex = (v >> 7) & 0xFF;   // bf16 exponent field
        if (ex >= 134) bad++;             // |x| >= 128 (or inf/nan)
    }
    atomicAdd(&cnt, bad);
    __syncthreads();
    if (threadIdx.x == 0) flag[0] = (cnt > 32) ? 1 : 0;
}

// ---------------- K1a: W transpose + hi/lo split ----------------
__global__ __launch_bounds__(256) void wsplit_kernel(
    const void* __restrict__ W0, const void* __restrict__ W1,
    const void* __restrict__ W2, const void* __restrict__ W3,
    u16* __restrict__ H0, u16* __restrict__ L0,
    u16* __restrict__ H1, u16* __restrict__ L1,
    u16* __restrict__ H2, u16* __restrict__ L2,
    u16* __restrict__ H3, u16* __restrict__ L3,
    const int* __restrict__ flagp)
{
    __shared__ float t[64][65];
    const int F  = *flagp;
    const int mz = blockIdx.z;
    const void* W = (mz == 0) ? W0 : (mz == 1) ? W1 : (mz == 2) ? W2 : W3;
    u16* H = (mz == 0) ? H0 : (mz == 1) ? H1 : (mz == 2) ? H2 : H3;
    u16* L = (mz == 0) ? L0 : (mz == 1) ? L1 : (mz == 2) ? L2 : L3;
    const int n0 = blockIdx.x * 64, k0 = blockIdx.y * 64;
    const int tid = threadIdx.x;

    #pragma unroll
    for (int i = 0; i < 4; ++i) {
        const int item = i * 256 + tid;
        const int r = item >> 4, c4 = (item & 15) * 4;
        if (F) {
            const float4 v = *(const float4*)((const float*)W + (k0 + r) * HIDC + n0 + c4);
            t[r][c4 + 0] = v.x; t[r][c4 + 1] = v.y; t[r][c4 + 2] = v.z; t[r][c4 + 3] = v.w;
        } else {
            #pragma unroll
            for (int j = 0; j < 4; ++j)
                t[r][c4 + j] = ldin(W, (k0 + r) * HIDC + n0 + c4 + j, 0);
        }
    }
    __syncthreads();
    #pragma unroll
    for (int i = 0; i < 4; ++i) {
        const int item = i * 256 + tid;
        const int r = item >> 4, c4 = (item & 15) * 4;   // r: n-offset, c4: k-offset
        ushort4 oh, ol;
        u16 h, l;
        split2(t[c4 + 0][r], h, l); oh.x = h; ol.x = l;
        split2(t[c4 + 1][r], h, l); oh.y = h; ol.y = l;
        split2(t[c4 + 2][r], h, l); oh.z = h; ol.z = l;
        split2(t[c4 + 3][r], h, l); oh.w = h; ol.w = l;
        *(ushort4*)&H[(n0 + r) * HIDC + k0 + c4] = oh;
        *(ushort4*)&L[(n0 + r) * HIDC + k0 + c4] = ol;
    }
}

// ---------------- K1b: activation hi/lo split (x) ----------------
__global__ __launch_bounds__(256) void xsplit_kernel(
    const void* __restrict__ src, u16* __restrict__ hi, u16* __restrict__ lo,
    const int* __restrict__ flagp)
{
    const int F = *flagp;
    const int i = blockIdx.x * 1024 + threadIdx.x * 4;
    float v[4];
    if (F) {
        const float4 f = *(const float4*)((const float*)src + i);
        v[0] = f.x; v[1] = f.y; v[2] = f.z; v[3] = f.w;
    } else {
        #pragma unroll
        for (int j = 0; j < 4; ++j) v[j] = ldin(src, i + j, 0);
    }
    ushort4 oh, ol;
    u16 h, l;
    split2(v[0], h, l); oh.x = h; ol.x = l;
    split2(v[1], h, l); oh.y = h; ol.y = l;
    split2(v[2], h, l); oh.z = h; ol.z = l;
    split2(v[3], h, l); oh.w = h; ol.w = l;
    *(ushort4*)&hi[i] = oh;
    *(ushort4*)&lo[i] = ol;
}

// ---------------- K1c: 3-term split-bf16 MFMA GEMM (unchanged) ----------------
template <int MODE>
__global__ __launch_bounds__(256) void mfma3_gemm_kernel(
    const u16* __restrict__ Ahi, const u16* __restrict__ Alo,
    const u16* __restrict__ B0h, const u16* __restrict__ B0l,
    const u16* __restrict__ B1h, const u16* __restrict__ B1l,
    const u16* __restrict__ B2h, const u16* __restrict__ B2l,
    const void* __restrict__ b0, const void* __restrict__ b1, const void* __restrict__ b2,
    const void* __restrict__ xres,
    float* __restrict__ O0, float* __restrict__ O1, float* __restrict__ O2,
    const int* __restrict__ flagp)
{
    __shared__ __align__(16) u16 smem[2 * 24576];   // 96 KB double buffer
    const int F    = *flagp;
    const int tid  = threadIdx.x;
    const int lane = tid & 63, wv = tid >> 6;
    const int m0 = blockIdx.y * 64;
    const int n0 = blockIdx.x * 128;

    const u16 *Bh, *Bl; const void* bias; float* Out; int col0;
    if (MODE == 0) {
        const int mat = n0 >> 10;
        col0 = n0 & 1023;
        Bh   = (mat == 0) ? B0h : (mat == 1) ? B1h : B2h;
        Bl   = (mat == 0) ? B0l : (mat == 1) ? B1l : B2l;
        bias = (mat == 0) ? b0  : (mat == 1) ? b1  : b2;
        Out  = (mat == 0) ? O0  : (mat == 1) ? O1  : O2;
    } else {
        col0 = n0; Bh = B0h; Bl = B0l; bias = b0; Out = O0;
    }

    const int rsub = lane >> 3;                        // row within chunk
    const int gsw  = ((lane & 7) ^ rsub) * 8;          // swizzled src granule (u16)
    const u16* pAh[2]; const u16* pAl[2];
    const u16* pBh[4]; const u16* pBl[4];
    int dA[2], dB[4];
    #pragma unroll
    for (int j = 0; j < 2; ++j) {
        const int c = wv * 2 + j;
        pAh[j] = Ahi + (m0 + c * 8 + rsub) * HIDC + gsw;
        pAl[j] = Alo + (m0 + c * 8 + rsub) * HIDC + gsw;
        dA[j]  = c * 512;
    }
    #pragma unroll
    for (int j = 0; j < 4; ++j) {
        const int c = wv * 4 + j;
        pBh[j] = Bh + (col0 + c * 8 + rsub) * HIDC + gsw;
        pBl[j] = Bl + (col0 + c * 8 + rsub) * HIDC + gsw;
        dB[j]  = c * 512;
    }

    int g16[2];
    #pragma unroll
    for (int kc = 0; kc < 2; ++kc) g16[kc] = (((kc * 4) + (lane >> 4)) ^ (lane & 7)) * 8;
    int afo[4], bfo[2];
    #pragma unroll
    for (int mi = 0; mi < 4; ++mi) afo[mi] = (mi * 16 + (lane & 15)) * 64;
    #pragma unroll
    for (int ni = 0; ni < 2; ++ni) bfo[ni] = (wv * 32 + ni * 16 + (lane & 15)) * 64;

    f32x4 zero = {0.f, 0.f, 0.f, 0.f};
    f32x4 acc[4][2];
    #pragma unroll
    for (int mi = 0; mi < 4; ++mi)
        #pragma unroll
        for (int ni = 0; ni < 2; ++ni) acc[mi][ni] = zero;

    #pragma unroll
    for (int j = 0; j < 2; ++j) {
        gload16(pAh[j], smem + dA[j]);
        gload16(pAl[j], smem + 4096 + dA[j]);
    }
    #pragma unroll
    for (int j = 0; j < 4; ++j) {
        gload16(pBh[j], smem + 8192  + dB[j]);
        gload16(pBl[j], smem + 16384 + dB[j]);
    }
    __syncthreads();

    for (int t = 0; t < 16; ++t) {
        const int bo = (t & 1) * 24576;
        if (t < 15) {
            const int bn = 24576 - bo;
            const int k  = (t + 1) * 64;
            #pragma unroll
            for (int j = 0; j < 2; ++j) {
                gload16(pAh[j] + k, smem + bn + dA[j]);
                gload16(pAl[j] + k, smem + bn + 4096 + dA[j]);
            }
            #pragma unroll
            for (int j = 0; j < 4; ++j) {
                gload16(pBh[j] + k, smem + bn + 8192  + dB[j]);
                gload16(pBl[j] + k, smem + bn + 16384 + dB[j]);
            }
        }
        #pragma unroll
        for (int kc = 0; kc < 2; ++kc) {
            bf16x8 ah[4], al[4], bh2[2], bl2[2];
            #pragma unroll
            for (int mi = 0; mi < 4; ++mi) {
                ah[mi] = *(const bf16x8*)(smem + bo +        afo[mi] + g16[kc]);
                al[mi] = *(const bf16x8*)(smem + bo + 4096 + afo[mi] + g16[kc]);
            }
            #pragma unroll
            for (int ni = 0; ni < 2; ++ni) {
                bh2[ni] = *(const bf16x8*)(smem + bo +  8192 + bfo[ni] + g16[kc]);
                bl2[ni] = *(const bf16x8*)(smem + bo + 16384 + bfo[ni] + g16[kc]);
            }
            #pragma unroll
            for (int mi = 0; mi < 4; ++mi)
                #pragma unroll
                for (int ni = 0; ni < 2; ++ni) {
                    acc[mi][ni] = __builtin_amdgcn_mfma_f32_16x16x32_bf16(
                        ah[mi], bh2[ni], acc[mi][ni], 0, 0, 0);
                    acc[mi][ni] = __builtin_amdgcn_mfma_f32_16x16x32_bf16(
                        ah[mi], bl2[ni], acc[mi][ni], 0, 0, 0);
                    acc[mi][ni] = __builtin_amdgcn_mfma_f32_16x16x32_bf16(
                        al[mi], bh2[ni], acc[mi][ni], 0, 0, 0);
                }
        }
        __syncthreads();
    }

    #pragma unroll
    for (int ni = 0; ni < 2; ++ni) {
        const int col = col0 + wv * 32 + ni * 16 + (lane & 15);
        const float bval = ldin(bias, col, F);
        #pragma unroll
        for (int mi = 0; mi < 4; ++mi) {
            const int row0 = m0 + mi * 16 + (lane >> 4) * 4;
            #pragma unroll
            for (int r = 0; r < 4; ++r) {
                const int row = row0 + r;
                float v = acc[mi][ni][r] + bval;
                if (MODE == 1) v += ldin(xres, row * HIDC + col, F);
                Out[row * HIDC + col] = v;
            }
        }
    }
}

// ---------------- K2: rfft(64) + amplitude norm -> split-bf16, padded ----------------
// Out: [h][s][128] u16 (hi & lo arrays): [0..33)=Re, [33..66)=Im, [66..128)=0
__global__ __launch_bounds__(64) void spectral_kernel(
    const float* __restrict__ Q, const float* __restrict__ K,
    u16* __restrict__ Qsh, u16* __restrict__ Qsl,
    u16* __restrict__ Ksh, u16* __restrict__ Ksl)
{
    __shared__ float qv[64];
    __shared__ float tc[64], tsn[64];
    const int unit = blockIdx.x;          // s*16 + h
    const int sel  = blockIdx.y;          // 0: Q, 1: K
    const int s = unit >> 4, h = unit & 15;
    const float* src = sel ? K : Q;
    u16* dh = sel ? Ksh : Qsh;
    u16* dl = sel ? Ksl : Qsl;
    const int t = threadIdx.x;

    qv[t] = src[s * HIDC + h * HDIM + t];
    float sv, cv;
    sincosf((float)t * (6.283185307179586f / 64.0f), &sv, &cv);
    tc[t] = cv; tsn[t] = sv;
    __syncthreads();

    const int base = (h * SEQ + s) * NFP;
    if (t < NFREQ) {
        float re = 0.0f, im = 0.0f;
        #pragma unroll
        for (int k = 0; k < 64; ++k) {
            const int idx = (t * k) & 63;
            re = fmaf(qv[k], tc[idx], re);
            im = fmaf(qv[k], -tsn[idx], im);
        }
        const float a  = sqrtf(re * re + im * im);
        const float sc = (a > 0.0f) ? rsqrtf(a) : 0.0f;
        u16 hh, ll;
        split2(re * sc, hh, ll);
        dh[base + t] = hh; dl[base + t] = ll;
        split2(im * sc, hh, ll);
        dh[base + NFREQ + t] = hh; dl[base + NFREQ + t] = ll;
    }
    if (t < 62) {   // zero pad 66..127
        dh[base + 66 + t] = 0; dl[base + 66 + t] = 0;
    }
}

// ---------------- K2b: V transpose + hi/lo split ----------------
// V f32 [512][1024] -> VTh/VTl [h][64 d][512 s] bf16
__global__ __launch_bounds__(256) void vtr_kernel(
    const float* __restrict__ V, u16* __restrict__ VTh, u16* __restrict__ VTl)
{
    __shared__ float t[64][65];
    const int s0 = blockIdx.x * 64, c0 = blockIdx.y * 64;   // c0 = h*64
    const int tid = threadIdx.x;
    #pragma unroll
    for (int i = 0; i < 4; ++i) {
        const int item = i * 256 + tid;
        const int r = item >> 4, c4 = (item & 15) * 4;
        const float4 v = *(const float4*)&V[(s0 + r) * HIDC + c0 + c4];
        t[r][c4 + 0] = v.x; t[r][c4 + 1] = v.y; t[r][c4 + 2] = v.z; t[r][c4 + 3] = v.w;
    }
    __syncthreads();
    #pragma unroll
    for (int i = 0; i < 4; ++i) {
        const int item = i * 256 + tid;
        const int d = item >> 4, s4 = (item & 15) * 4;
        ushort4 oh, ol;
        u16 h, l;
        split2(t[s4 + 0][d], h, l); oh.x = h; ol.x = l;
        split2(t[s4 + 1][d], h, l); oh.y = h; ol.y = l;
        split2(t[s4 + 2][d], h, l); oh.z = h; ol.z = l;
        split2(t[s4 + 3][d], h, l); oh.w = h; ol.w = l;
        *(ushort4*)&VTh[(c0 + d) * SEQ + s0 + s4] = oh;
        *(ushort4*)&VTl[(c0 + d) * SEQ + s0 + s4] = ol;
    }
}

// ---------------- K3: MFMA attention ----------------
// 2 waves x 16 q-rows; grid (SEQ/32, NH).
// Phase 1: S^T = Kn @ Qn^T via mfma (3-term). Lane owns q = lane&15; full S^T
// (512 k) in 32 f32x4 regs. Softmax: 2 shfl_xor reductions (k lane-local).
// Phase 2: P (split hi/lo) -> LDS per 128-k chunk; ctx = P @ VT^T via mfma.
// Output: chi/clo (split bf16 ctx) directly.
__global__ __launch_bounds__(128) void attn_mfma_kernel(
    const u16* __restrict__ Qsh, const u16* __restrict__ Qsl,
    const u16* __restrict__ Ksh, const u16* __restrict__ Ksl,
    const u16* __restrict__ VTh, const u16* __restrict__ VTl,
    const int* __restrict__ mask, const void* __restrict__ temp_p,
    u16* __restrict__ chi, u16* __restrict__ clo,
    const int* __restrict__ flagp)
{
    __shared__ __align__(16) u16 smem[32768];   // 64 KB (phase-1 K | phase-2 VT+P)
    __shared__ int   mask_lds[512];
    __shared__ float l_lds[2][16];

    const int F    = *flagp;
    const int tid  = threadIdx.x;
    const int lane = tid & 63, w = tid >> 6;
    const int hi = lane >> 4, q15 = lane & 15, l7 = lane & 7;
    const int rc = lane >> 4;                    // row-in-chunk for staging
    const int h  = blockIdx.y, q0 = blockIdx.x * 32;
    const float temp = ldin(temp_p, 0, F);

    *(int4*)&mask_lds[tid * 4] = *(const int4*)&mask[tid * 4];

    // Q B-fragments from global (entity = q15, f-chunk = hi)
    bf16x8 qfh[3], qfl[3];
    {
        const int qrow = (h * SEQ + q0 + w * 16 + q15) * NFP;
        #pragma unroll
        for (int kc = 0; kc < 3; ++kc) {
            qfh[kc] = *(const bf16x8*)(Qsh + qrow + kc * 32 + hi * 8);
            qfl[kc] = *(const bf16x8*)(Qsl + qrow + kc * 32 + hi * 8);
        }
    }

    f32x4 sT[32];
    #pragma unroll
    for (int t = 0; t < 32; ++t) sT[t] = f32x4{0.f, 0.f, 0.f, 0.f};

    // ---- phase 1: S^T, K staged 128 keys/iter at [row][128f] swizzled ----
    constexpr int KH = 0, KL = 16384;
    #pragma unroll
    for (int kt = 0; kt < 4; ++kt) {
        __syncthreads();   // prior reads done (and mask_lds visible at kt=0)
        #pragma unroll
        for (int j = 0; j < 16; ++j) {
            const int row = w * 64 + j * 4 + rc;
            const int soff = (h * SEQ + kt * 128 + row) * NFP + ((q15 ^ (row & 7)) * 8);
            gload16(Ksh + soff, smem + KH + (w * 64 + j * 4) * 128);
            gload16(Ksl + soff, smem + KL + (w * 64 + j * 4) * 128);
        }
        __syncthreads();   // staged (drains vmcnt)
        #pragma unroll
        for (int tt = 0; tt < 8; ++tt) {
            const int t = kt * 8 + tt;
            #pragma unroll
            for (int kc = 0; kc < 3; ++kc) {
                const int ro = (tt * 16 + q15) * 128 + (((kc * 4 + hi) ^ l7) * 8);
                const bf16x8 ah = *(const bf16x8*)(smem + KH + ro);
                const bf16x8 al = *(const bf16x8*)(smem + KL + ro);
                sT[t] = __builtin_amdgcn_mfma_f32_16x16x32_bf16(ah, qfh[kc], sT[t], 0, 0, 0);
                sT[t] = __builtin_amdgcn_mfma_f32_16x16x32_bf16(ah, qfl[kc], sT[t], 0, 0, 0);
                sT[t] = __builtin_amdgcn_mfma_f32_16x16x32_bf16(al, qfh[kc], sT[t], 0, 0, 0);
            }
        }
    }
    __syncthreads();   // last K reads done before phase-2 overwrites

    // ---- softmax (k lane-local per q = lane&15) ----
    float m = -1e30f;
    #pragma unroll
    for (int t = 0; t < 32; ++t) {
        const int4 mv = *(const int4*)&mask_lds[t * 16 + hi * 4];
        float s;
        s = (mv.x == 0) ? -1e9f : sT[t][0] * temp; sT[t][0] = s; m = fmaxf(m, s);
        s = (mv.y == 0) ? -1e9f : sT[t][1] * temp; sT[t][1] = s; m = fmaxf(m, s);
        s = (mv.z == 0) ? -1e9f : sT[t][2] * temp; sT[t][2] = s; m = fmaxf(m, s);
        s = (mv.w == 0) ? -1e9f : sT[t][3] * temp; sT[t][3] = s; m = fmaxf(m, s);
    }
    m = fmaxf(m, __shfl_xor(m, 16, 64));
    m = fmaxf(m, __shfl_xor(m, 32, 64));
    float sum = 0.0f;
    #pragma unroll
    for (int t = 0; t < 32; ++t) {
        #pragma unroll
        for (int r = 0; r < 4; ++r) {
            const float p = __expf(sT[t][r] - m);
            sT[t][r] = p;
            sum += p;
        }
    }
    sum += __shfl_xor(sum, 16, 64);
    sum += __shfl_xor(sum, 32, 64);
    if (lane < 16) l_lds[w][q15] = sum;

    // ---- phase 2: PV, VT staged 128 keys/chunk; P hi/lo to LDS ----
    constexpr int VH = 0, VL = 8192, PB = 16384;
    const int PHo = PB + w * 4352;          // [16][136] u16
    const int PLo = PHo + 2176;
    f32x4 acc[4];
    #pragma unroll
    for (int dt = 0; dt < 4; ++dt) acc[dt] = f32x4{0.f, 0.f, 0.f, 0.f};

    #pragma unroll
    for (int c = 0; c < 4; ++c) {
        __syncthreads();   // prior chunk's VT/P reads done
        #pragma unroll
        for (int j = 0; j < 8; ++j) {
            const int d = w * 32 + j * 4 + rc;
            const int soff = (h * HDIM + d) * SEQ + c * 128 + ((q15 ^ (d & 7)) * 8);
            gload16(VTh + soff, smem + VH + (w * 32 + j * 4) * 128);
            gload16(VTl + soff, smem + VL + (w * 32 + j * 4) * 128);
        }
        #pragma unroll
        for (int tt = 0; tt < 8; ++tt) {
            const int t = c * 8 + tt;
            ushort4 ph, pl;
            u16 hh, ll;
            split2(sT[t][0], hh, ll); ph.x = hh; pl.x = ll;
            split2(sT[t][1], hh, ll); ph.y = hh; pl.y = ll;
            split2(sT[t][2], hh, ll); ph.z = hh; pl.z = ll;
            split2(sT[t][3], hh, ll); ph.w = hh; pl.w = ll;
            const int po = q15 * 136 + tt * 16 + hi * 4;
            *(ushort4*)(smem + PHo + po) = ph;
            *(ushort4*)(smem + PLo + po) = pl;
        }
        __syncthreads();   // VT staged (drains vmcnt); P visible
        #pragma unroll
        for (int dt = 0; dt < 4; ++dt) {
            #pragma unroll
            for (int kc = 0; kc < 4; ++kc) {
                const int po = q15 * 136 + kc * 32 + hi * 8;
                const bf16x8 pfh = *(const bf16x8*)(smem + PHo + po);
                const bf16x8 pfl = *(const bf16x8*)(smem + PLo + po);
                const int vo = (dt * 16 + q15) * 128 + (((kc * 4 + hi) ^ l7) * 8);
                const bf16x8 vfh = *(const bf16x8*)(smem + VH + vo);
                const bf16x8 vfl = *(const bf16x8*)(smem + VL + vo);
                acc[dt] = __builtin_amdgcn_mfma_f32_16x16x32_bf16(pfh, vfh, acc[dt], 0, 0, 0);
                acc[dt] = __builtin_amdgcn_mfma_f32_16x16x32_bf16(pfl, vfh, acc[dt], 0, 0, 0);
                acc[dt] = __builtin_amdgcn_mfma_f32_16x16x32_bf16(pfh, vfl, acc[dt], 0, 0, 0);
            }
        }
    }

    // ---- epilogue: ctx = acc / l, split to chi/clo ----
    const float4 lv = *(const float4*)&l_lds[w][hi * 4];
    const float lr[4] = {1.0f / lv.x, 1.0f / lv.y, 1.0f / lv.z, 1.0f / lv.w};
    #pragma unroll
    for (int dt = 0; dt < 4; ++dt) {
        #pragma unroll
        for (int r = 0; r < 4; ++r) {
            const float v = acc[dt][r] * lr[r];
            u16 hh, ll;
            split2(v, hh, ll);
            const int row = q0 + w * 16 + hi * 4 + r;
            const int col = h * HDIM + dt * 16 + q15;
            chi[row * HIDC + col] = hh;
            clo[row * HIDC + col] = ll;
        }
    }
}

// ---------------- K5: LayerNorm -> out ----------------
__global__ __launch_bounds__(256) void ln_kernel(
    const float* __restrict__ Y, const void* __restrict__ gamma,
    const void* __restrict__ beta, void* __restrict__ out,
    const int* __restrict__ flagp)
{
    const int F = *flagp;
    const int row = blockIdx.x, tid = threadIdx.x;
    float v[4];
    float s = 0.0f, s2 = 0.0f;
    #pragma unroll
    for (int j = 0; j < 4; ++j) {
        v[j] = Y[row * HIDC + tid + j * 256];
        s += v[j]; s2 += v[j] * v[j];
    }
    #pragma unroll
    for (int off = 32; off > 0; off >>= 1) {
        s  += __shfl_xor(s, off, 64);
        s2 += __shfl_xor(s2, off, 64);
    }
    __shared__ float wred[4][2];
    const int w = tid >> 6;
    if ((tid & 63) == 0) { wred[w][0] = s; wred[w][1] = s2; }
    __syncthreads();
    s  = wred[0][0] + wred[1][0] + wred[2][0] + wred[3][0];
    s2 = wred[0][1] + wred[1][1] + wred[2][1] + wred[3][1];
    const float mu   = s / (float)HIDC;
    const float var  = s2 / (float)HIDC - mu * mu;
    const float rstd = rsqrtf(var + 1e-5f);
    #pragma unroll
    for (int j = 0; j < 4; ++j) {
        const int c = tid + j * 256;
        const float g = ldin(gamma, c, F), b = ldin(beta, c, F);
        const float r = (v[j] - mu) * rstd * g + b;
        if (F) ((float*)out)[row * HIDC + c] = r;
        else   ((__hip_bfloat16*)out)[row * HIDC + c] = __float2bfloat16(r);
    }
}

extern "C" void kernel_launch(void* const* d_in, const int* in_sizes, int n_in,
                              void* d_out, int out_size, void* d_ws, size_t ws_size,
                              hipStream_t stream) {
    const void* x    = d_in[0];
    const int*  mask = (const int*)d_in[1];
    const void* Wq   = d_in[2];
    const void* bq   = d_in[3];
    const void* Wk   = d_in[4];
    const void* bk   = d_in[5];
    const void* Wv   = d_in[6];
    const void* bv   = d_in[7];
    const void* Wo   = d_in[8];
    const void* bo   = d_in[9];
    const void* temp = d_in[10];
    const void* gam  = d_in[11];
    const void* bet  = d_in[12];

    float* ws   = (float*)d_ws;
    int*   flag = (int*)ws;                  // 16B reserved
    float* Q    = ws + 4;                    // 512*1024 f32
    float* K    = Q   + SEQ * HIDC;
    float* V    = K   + SEQ * HIDC;
    float* Y    = V   + SEQ * HIDC;          // 512*1024 f32
    u16*   xhi  = (u16*)(Y + SEQ * HIDC);    // 512*1024 bf16 each
    u16*   xlo  = xhi + SEQ * HIDC;
    u16*   chi  = xlo + SEQ * HIDC;
    u16*   clo  = chi + SEQ * HIDC;
    u16*   Wqh  = clo + SEQ * HIDC;          // 8 x 1024*1024 bf16
    u16*   Wql  = Wqh + HIDC * HIDC;
    u16*   Wkh  = Wql + HIDC * HIDC;
    u16*   Wkl  = Wkh + HIDC * HIDC;
    u16*   Wvh  = Wkl + HIDC * HIDC;
    u16*   Wvl  = Wvh + HIDC * HIDC;
    u16*   Woh  = Wvl + HIDC * HIDC;
    u16*   Wol  = Woh + HIDC * HIDC;
    u16*   Qsh  = Wol + HIDC * HIDC;         // 4 x 16*512*128 bf16 (padded spectra)
    u16*   Qsl  = Qsh + NH * SEQ * NFP;
    u16*   Ksh  = Qsl + NH * SEQ * NFP;
    u16*   Ksl  = Ksh + NH * SEQ * NFP;
    u16*   VTh  = Ksl + NH * SEQ * NFP;      // 2 x 16*64*512 bf16
    u16*   VTl  = VTh + NH * HDIM * SEQ;

    sniff_kernel<<<1, 256, 0, stream>>>(Wq, flag);

    // prep: W transpose+split, x split
    wsplit_kernel<<<dim3(16, 16, 4), 256, 0, stream>>>(
        Wq, Wk, Wv, Wo, Wqh, Wql, Wkh, Wkl, Wvh, Wvl, Woh, Wol, flag);
    xsplit_kernel<<<512, 256, 0, stream>>>(x, xhi, xlo, flag);

    // QKV projection (split-bf16 MFMA, fp32 out)
    mfma3_gemm_kernel<0><<<dim3(24, 8), 256, 0, stream>>>(
        xhi, xlo, Wqh, Wql, Wkh, Wkl, Wvh, Wvl,
        bq, bk, bv, nullptr, Q, K, V, flag);

    // spectra (split-bf16 padded) + V transpose (split-bf16)
    spectral_kernel<<<dim3(SEQ * NH, 2), 64, 0, stream>>>(Q, K, Qsh, Qsl, Ksh, Ksl);
    vtr_kernel<<<dim3(8, 16), 256, 0, stream>>>(V, VTh, VTl);

    // attention (MFMA), writes split ctx directly
    attn_mfma_kernel<<<dim3(SEQ / 32, NH), 128, 0, stream>>>(
        Qsh, Qsl, Ksh, Ksl, VTh, VTl, mask, temp, chi, clo, flag);

    // O-projection (+bias+residual)
    mfma3_gemm_kernel<1><<<dim3(8, 8), 256, 0, stream>>>(
        chi, clo, Woh, Wol, nullptr, nullptr, nullptr, nullptr,
        bo, nullptr, nullptr, x, Y, nullptr, nullptr, flag);

    ln_kernel<<<SEQ, 256, 0, stream>>>(Y, gam, bet, d_out, flag);
}

// Round 5
// 182.126 us; speedup vs baseline: 2.6279x; 1.0252x over previous
//
#include <hip/hip_runtime.h>
#include <hip/hip_bf16.h>
#include <math.h>

constexpr int SEQ   = 512;
constexpr int HIDC  = 1024;
constexpr int NH    = 16;
constexpr int HDIM  = 64;
constexpr int NFREQ = 33;   // rfft bins for n=64
constexpr int NFP   = 128;  // padded packed spectral length (66 -> 128, zero pad)

typedef unsigned short u16;
typedef __bf16 bf16x8 __attribute__((ext_vector_type(8)));
typedef float  f32x4  __attribute__((ext_vector_type(4)));

typedef __attribute__((address_space(3))) void       as3_void;
typedef __attribute__((address_space(1))) const void as1_void;

// async global->LDS, 16B per lane; LDS dest = wave-uniform base + lane*16
__device__ __forceinline__ void gload16(const u16* g, u16* l) {
    __builtin_amdgcn_global_load_lds((as1_void*)g, (as3_void*)l, 16, 0, 0);
}

// dtype-agnostic input load: f32 ? float : bf16
__device__ __forceinline__ float ldin(const void* p, int i, int f32) {
    if (f32) return ((const float*)p)[i];
    return __bfloat162float(((const __hip_bfloat16*)p)[i]);
}

__device__ __forceinline__ u16 f2b(float f) {   // RNE fp32 -> bf16 bits
    unsigned int u = __builtin_bit_cast(unsigned int, f);
    u += 0x7fffu + ((u >> 16) & 1u);
    return (u16)(u >> 16);
}
__device__ __forceinline__ float b2f(u16 b) {
    return __builtin_bit_cast(float, (unsigned int)b << 16);
}
// fp32 -> (hi, lo) bf16 pair; hi + lo ~ f to ~16 mantissa bits
__device__ __forceinline__ void split2(float f, u16& hi, u16& lo) {
    hi = f2b(f);
    lo = f2b(f - b2f(hi));
}

// ---------------- K0: dtype sniff ----------------
__global__ void sniff_kernel(const void* w, int* flag) {
    __shared__ int cnt;
    if (threadIdx.x == 0) cnt = 0;
    __syncthreads();
    const unsigned short* h = (const unsigned short*)w;
    int bad = 0;
    for (int i = threadIdx.x; i < 512; i += 256) {
        const unsigned short v = h[i];
        const int ex = (v >> 7) & 0xFF;   // bf16 exponent field
        if (ex >= 134) bad++;             // |x| >= 128 (or inf/nan)
    }
    atomicAdd(&cnt, bad);
    __syncthreads();
    if (threadIdx.x == 0) flag[0] = (cnt > 32) ? 1 : 0;
}

// ---------------- K1a: prep = W transpose+split (z<4) | x split (z==4) ----------------
__global__ __launch_bounds__(256) void prep_kernel(
    const void* __restrict__ W0, const void* __restrict__ W1,
    const void* __restrict__ W2, const void* __restrict__ W3,
    u16* __restrict__ H0, u16* __restrict__ L0,
    u16* __restrict__ H1, u16* __restrict__ L1,
    u16* __restrict__ H2, u16* __restrict__ L2,
    u16* __restrict__ H3, u16* __restrict__ L3,
    const void* __restrict__ xsrc, u16* __restrict__ xhi, u16* __restrict__ xlo,
    const int* __restrict__ flagp)
{
    const int F  = *flagp;
    const int mz = blockIdx.z;

    if (mz == 4) {   // x split: 256 blocks x 256 thr x 8 elems
        const int blk = blockIdx.y * 16 + blockIdx.x;
        const int i0  = blk * 2048 + threadIdx.x * 8;
        #pragma unroll
        for (int g = 0; g < 2; ++g) {
            const int i = i0 + g * 4;
            float v[4];
            if (F) {
                const float4 f = *(const float4*)((const float*)xsrc + i);
                v[0] = f.x; v[1] = f.y; v[2] = f.z; v[3] = f.w;
            } else {
                #pragma unroll
                for (int j = 0; j < 4; ++j) v[j] = ldin(xsrc, i + j, 0);
            }
            ushort4 oh, ol;
            u16 h, l;
            split2(v[0], h, l); oh.x = h; ol.x = l;
            split2(v[1], h, l); oh.y = h; ol.y = l;
            split2(v[2], h, l); oh.z = h; ol.z = l;
            split2(v[3], h, l); oh.w = h; ol.w = l;
            *(ushort4*)&xhi[i] = oh;
            *(ushort4*)&xlo[i] = ol;
        }
        return;
    }

    __shared__ float t[64][65];
    const void* W = (mz == 0) ? W0 : (mz == 1) ? W1 : (mz == 2) ? W2 : W3;
    u16* H = (mz == 0) ? H0 : (mz == 1) ? H1 : (mz == 2) ? H2 : H3;
    u16* L = (mz == 0) ? L0 : (mz == 1) ? L1 : (mz == 2) ? L2 : L3;
    const int n0 = blockIdx.x * 64, k0 = blockIdx.y * 64;
    const int tid = threadIdx.x;

    #pragma unroll
    for (int i = 0; i < 4; ++i) {
        const int item = i * 256 + tid;
        const int r = item >> 4, c4 = (item & 15) * 4;
        if (F) {
            const float4 v = *(const float4*)((const float*)W + (k0 + r) * HIDC + n0 + c4);
            t[r][c4 + 0] = v.x; t[r][c4 + 1] = v.y; t[r][c4 + 2] = v.z; t[r][c4 + 3] = v.w;
        } else {
            #pragma unroll
            for (int j = 0; j < 4; ++j)
                t[r][c4 + j] = ldin(W, (k0 + r) * HIDC + n0 + c4 + j, 0);
        }
    }
    __syncthreads();
    #pragma unroll
    for (int i = 0; i < 4; ++i) {
        const int item = i * 256 + tid;
        const int r = item >> 4, c4 = (item & 15) * 4;   // r: n-offset, c4: k-offset
        ushort4 oh, ol;
        u16 h, l;
        split2(t[c4 + 0][r], h, l); oh.x = h; ol.x = l;
        split2(t[c4 + 1][r], h, l); oh.y = h; ol.y = l;
        split2(t[c4 + 2][r], h, l); oh.z = h; ol.z = l;
        split2(t[c4 + 3][r], h, l); oh.w = h; ol.w = l;
        *(ushort4*)&H[(n0 + r) * HIDC + k0 + c4] = oh;
        *(ushort4*)&L[(n0 + r) * HIDC + k0 + c4] = ol;
    }
}

// ---------------- K1c: 3-term split-bf16 MFMA GEMM (unchanged, verified) ----------------
template <int MODE>
__global__ __launch_bounds__(256) void mfma3_gemm_kernel(
    const u16* __restrict__ Ahi, const u16* __restrict__ Alo,
    const u16* __restrict__ B0h, const u16* __restrict__ B0l,
    const u16* __restrict__ B1h, const u16* __restrict__ B1l,
    const u16* __restrict__ B2h, const u16* __restrict__ B2l,
    const void* __restrict__ b0, const void* __restrict__ b1, const void* __restrict__ b2,
    const void* __restrict__ xres,
    float* __restrict__ O0, float* __restrict__ O1, float* __restrict__ O2,
    const int* __restrict__ flagp)
{
    __shared__ __align__(16) u16 smem[2 * 24576];   // 96 KB double buffer
    const int F    = *flagp;
    const int tid  = threadIdx.x;
    const int lane = tid & 63, wv = tid >> 6;
    const int m0 = blockIdx.y * 64;
    const int n0 = blockIdx.x * 128;

    const u16 *Bh, *Bl; const void* bias; float* Out; int col0;
    if (MODE == 0) {
        const int mat = n0 >> 10;
        col0 = n0 & 1023;
        Bh   = (mat == 0) ? B0h : (mat == 1) ? B1h : B2h;
        Bl   = (mat == 0) ? B0l : (mat == 1) ? B1l : B2l;
        bias = (mat == 0) ? b0  : (mat == 1) ? b1  : b2;
        Out  = (mat == 0) ? O0  : (mat == 1) ? O1  : O2;
    } else {
        col0 = n0; Bh = B0h; Bl = B0l; bias = b0; Out = O0;
    }

    const int rsub = lane >> 3;
    const int gsw  = ((lane & 7) ^ rsub) * 8;
    const u16* pAh[2]; const u16* pAl[2];
    const u16* pBh[4]; const u16* pBl[4];
    int dA[2], dB[4];
    #pragma unroll
    for (int j = 0; j < 2; ++j) {
        const int c = wv * 2 + j;
        pAh[j] = Ahi + (m0 + c * 8 + rsub) * HIDC + gsw;
        pAl[j] = Alo + (m0 + c * 8 + rsub) * HIDC + gsw;
        dA[j]  = c * 512;
    }
    #pragma unroll
    for (int j = 0; j < 4; ++j) {
        const int c = wv * 4 + j;
        pBh[j] = Bh + (col0 + c * 8 + rsub) * HIDC + gsw;
        pBl[j] = Bl + (col0 + c * 8 + rsub) * HIDC + gsw;
        dB[j]  = c * 512;
    }

    int g16[2];
    #pragma unroll
    for (int kc = 0; kc < 2; ++kc) g16[kc] = (((kc * 4) + (lane >> 4)) ^ (lane & 7)) * 8;
    int afo[4], bfo[2];
    #pragma unroll
    for (int mi = 0; mi < 4; ++mi) afo[mi] = (mi * 16 + (lane & 15)) * 64;
    #pragma unroll
    for (int ni = 0; ni < 2; ++ni) bfo[ni] = (wv * 32 + ni * 16 + (lane & 15)) * 64;

    f32x4 zero = {0.f, 0.f, 0.f, 0.f};
    f32x4 acc[4][2];
    #pragma unroll
    for (int mi = 0; mi < 4; ++mi)
        #pragma unroll
        for (int ni = 0; ni < 2; ++ni) acc[mi][ni] = zero;

    #pragma unroll
    for (int j = 0; j < 2; ++j) {
        gload16(pAh[j], smem + dA[j]);
        gload16(pAl[j], smem + 4096 + dA[j]);
    }
    #pragma unroll
    for (int j = 0; j < 4; ++j) {
        gload16(pBh[j], smem + 8192  + dB[j]);
        gload16(pBl[j], smem + 16384 + dB[j]);
    }
    __syncthreads();

    for (int t = 0; t < 16; ++t) {
        const int bo = (t & 1) * 24576;
        if (t < 15) {
            const int bn = 24576 - bo;
            const int k  = (t + 1) * 64;
            #pragma unroll
            for (int j = 0; j < 2; ++j) {
                gload16(pAh[j] + k, smem + bn + dA[j]);
                gload16(pAl[j] + k, smem + bn + 4096 + dA[j]);
            }
            #pragma unroll
            for (int j = 0; j < 4; ++j) {
                gload16(pBh[j] + k, smem + bn + 8192  + dB[j]);
                gload16(pBl[j] + k, smem + bn + 16384 + dB[j]);
            }
        }
        #pragma unroll
        for (int kc = 0; kc < 2; ++kc) {
            bf16x8 ah[4], al[4], bh2[2], bl2[2];
            #pragma unroll
            for (int mi = 0; mi < 4; ++mi) {
                ah[mi] = *(const bf16x8*)(smem + bo +        afo[mi] + g16[kc]);
                al[mi] = *(const bf16x8*)(smem + bo + 4096 + afo[mi] + g16[kc]);
            }
            #pragma unroll
            for (int ni = 0; ni < 2; ++ni) {
                bh2[ni] = *(const bf16x8*)(smem + bo +  8192 + bfo[ni] + g16[kc]);
                bl2[ni] = *(const bf16x8*)(smem + bo + 16384 + bfo[ni] + g16[kc]);
            }
            #pragma unroll
            for (int mi = 0; mi < 4; ++mi)
                #pragma unroll
                for (int ni = 0; ni < 2; ++ni) {
                    acc[mi][ni] = __builtin_amdgcn_mfma_f32_16x16x32_bf16(
                        ah[mi], bh2[ni], acc[mi][ni], 0, 0, 0);
                    acc[mi][ni] = __builtin_amdgcn_mfma_f32_16x16x32_bf16(
                        ah[mi], bl2[ni], acc[mi][ni], 0, 0, 0);
                    acc[mi][ni] = __builtin_amdgcn_mfma_f32_16x16x32_bf16(
                        al[mi], bh2[ni], acc[mi][ni], 0, 0, 0);
                }
        }
        __syncthreads();
    }

    #pragma unroll
    for (int ni = 0; ni < 2; ++ni) {
        const int col = col0 + wv * 32 + ni * 16 + (lane & 15);
        const float bval = ldin(bias, col, F);
        #pragma unroll
        for (int mi = 0; mi < 4; ++mi) {
            const int row0 = m0 + mi * 16 + (lane >> 4) * 4;
            #pragma unroll
            for (int r = 0; r < 4; ++r) {
                const int row = row0 + r;
                float v = acc[mi][ni][r] + bval;
                if (MODE == 1) v += ldin(xres, row * HIDC + col, F);
                Out[row * HIDC + col] = v;
            }
        }
    }
}

// ---------------- K2: rfft(64) + amplitude norm -> split-bf16, padded ----------------
__global__ __launch_bounds__(64) void spectral_kernel(
    const float* __restrict__ Q, const float* __restrict__ K,
    u16* __restrict__ Qsh, u16* __restrict__ Qsl,
    u16* __restrict__ Ksh, u16* __restrict__ Ksl)
{
    __shared__ float qv[64];
    __shared__ float tc[64], tsn[64];
    const int unit = blockIdx.x;          // s*16 + h
    const int sel  = blockIdx.y;          // 0: Q, 1: K
    const int s = unit >> 4, h = unit & 15;
    const float* src = sel ? K : Q;
    u16* dh = sel ? Ksh : Qsh;
    u16* dl = sel ? Ksl : Qsl;
    const int t = threadIdx.x;

    qv[t] = src[s * HIDC + h * HDIM + t];
    float sv, cv;
    sincosf((float)t * (6.283185307179586f / 64.0f), &sv, &cv);
    tc[t] = cv; tsn[t] = sv;
    __syncthreads();

    const int base = (h * SEQ + s) * NFP;
    if (t < NFREQ) {
        float re = 0.0f, im = 0.0f;
        #pragma unroll
        for (int k = 0; k < 64; ++k) {
            const int idx = (t * k) & 63;
            re = fmaf(qv[k], tc[idx], re);
            im = fmaf(qv[k], -tsn[idx], im);
        }
        const float a  = sqrtf(re * re + im * im);
        const float sc = (a > 0.0f) ? rsqrtf(a) : 0.0f;
        u16 hh, ll;
        split2(re * sc, hh, ll);
        dh[base + t] = hh; dl[base + t] = ll;
        split2(im * sc, hh, ll);
        dh[base + NFREQ + t] = hh; dl[base + NFREQ + t] = ll;
    }
    if (t < 62) {   // zero pad 66..127
        dh[base + 66 + t] = 0; dl[base + 66 + t] = 0;
    }
}

// ---------------- K2b: V transpose + hi/lo split ----------------
__global__ __launch_bounds__(256) void vtr_kernel(
    const float* __restrict__ V, u16* __restrict__ VTh, u16* __restrict__ VTl)
{
    __shared__ float t[64][65];
    const int s0 = blockIdx.x * 64, c0 = blockIdx.y * 64;   // c0 = h*64
    const int tid = threadIdx.x;
    #pragma unroll
    for (int i = 0; i < 4; ++i) {
        const int item = i * 256 + tid;
        const int r = item >> 4, c4 = (item & 15) * 4;
        const float4 v = *(const float4*)&V[(s0 + r) * HIDC + c0 + c4];
        t[r][c4 + 0] = v.x; t[r][c4 + 1] = v.y; t[r][c4 + 2] = v.z; t[r][c4 + 3] = v.w;
    }
    __syncthreads();
    #pragma unroll
    for (int i = 0; i < 4; ++i) {
        const int item = i * 256 + tid;
        const int d = item >> 4, s4 = (item & 15) * 4;
        ushort4 oh, ol;
        u16 h, l;
        split2(t[s4 + 0][d], h, l); oh.x = h; ol.x = l;
        split2(t[s4 + 1][d], h, l); oh.y = h; ol.y = l;
        split2(t[s4 + 2][d], h, l); oh.z = h; ol.z = l;
        split2(t[s4 + 3][d], h, l); oh.w = h; ol.w = l;
        *(ushort4*)&VTh[(c0 + d) * SEQ + s0 + s4] = oh;
        *(ushort4*)&VTl[(c0 + d) * SEQ + s0 + s4] = ol;
    }
}

// ---------------- K3: MFMA attention, k-split waves + counted-vmcnt dbuf ----------------
// grid (SEQ/16, NH), 128 thr. Block = 16 q-rows; wave w owns k in [w*256, w*256+256).
// Per-wave 32KB LDS region (no cross-wave LDS use until merge) -> barrier-free
// double-buffered staging with s_waitcnt vmcnt(N) counted waits (T3/T4).
// Phase 1: S^T = mfma(K_frag, Q_frag) 3-term; lane owns q=lane&15, k lane-local.
// Softmax: 2-wave split-k reduce via LDS (m then l). Phase 2: PV 3-term, partial
// acc per wave, merged via LDS. Output: split bf16 ctx (chi/clo).
__global__ __launch_bounds__(128) void attn_mfma_kernel(
    const u16* __restrict__ Qsh, const u16* __restrict__ Qsl,
    const u16* __restrict__ Ksh, const u16* __restrict__ Ksl,
    const u16* __restrict__ VTh, const u16* __restrict__ VTl,
    const int* __restrict__ mask, const void* __restrict__ temp_p,
    u16* __restrict__ chi, u16* __restrict__ clo,
    const int* __restrict__ flagp)
{
    __shared__ __align__(16) u16 smem[32768];   // 64 KB: wave w owns [w*16384, +16384)
    __shared__ int   mask_lds[512];
    __shared__ float mpart[2][16], lpart[2][16], l_final[16];

    const int F    = *flagp;
    const int tid  = threadIdx.x;
    const int lane = tid & 63, w = tid >> 6;
    const int hi = lane >> 4, q15 = lane & 15, l7 = lane & 7;
    const int h  = blockIdx.y, q0 = blockIdx.x * 16;
    const int k0 = w * 256;                     // wave's k-half
    const int WB = w * 16384;                   // wave's LDS region (u16)
    const float temp = ldin(temp_p, 0, F);

    // each wave loads exactly the mask range it reads (no cross-wave dep)
    *(int4*)&mask_lds[tid * 4] = *(const int4*)&mask[tid * 4];

    // Q fragments (B operand): q = q0 + q15, k-granule (kc,hi)
    bf16x8 qfh[3], qfl[3];
    {
        const int qrow = (h * SEQ + q0 + q15) * NFP;
        #pragma unroll
        for (int kc = 0; kc < 3; ++kc) {
            qfh[kc] = *(const bf16x8*)(Qsh + qrow + kc * 32 + hi * 8);
            qfl[kc] = *(const bf16x8*)(Qsl + qrow + kc * 32 + hi * 8);
        }
    }

    const int rc4 = lane >> 4;   // row-in-quad for K staging

    // stage K chunk (32 rows x 128f, hi+lo) into buf b: KH @ WB+b*8192, KL @ +4096
    auto stageK = [&](int kt, int b) {
        const int base = WB + b * 8192;
        #pragma unroll
        for (int j = 0; j < 8; ++j) {
            const int row = j * 4 + rc4;
            const int gs  = (q15 ^ (row & 7)) * 8;
            const int so  = (h * SEQ + k0 + kt * 32 + row) * NFP + gs;
            gload16(Ksh + so, smem + base + j * 512);
            gload16(Ksl + so, smem + base + 4096 + j * 512);
        }
    };
    // stage VT chunk (64 d x 32 k, hi+lo) into buf b: VTH @ WB+b*4096, VTL @ +2048
    auto stageV = [&](int c, int b) {
        const int base = WB + b * 4096;
        #pragma unroll
        for (int j = 0; j < 4; ++j) {
            const int d  = j * 16 + (lane >> 2);
            const int gs = ((lane & 3) ^ (d & 3)) * 8;
            const int so = (h * HDIM + d) * SEQ + k0 + c * 32 + gs;
            gload16(VTh + so, smem + base + j * 512);
            gload16(VTl + so, smem + base + 2048 + j * 512);
        }
    };

    f32x4 sT[16];
    #pragma unroll
    for (int t = 0; t < 16; ++t) sT[t] = f32x4{0.f, 0.f, 0.f, 0.f};

    // ---- phase 1: barrier-free per-wave double-buffered K ----
    stageK(0, 0);
    #pragma unroll
    for (int kt = 0; kt < 8; ++kt) {
        if (kt < 7) {
            stageK(kt + 1, (kt + 1) & 1);
            asm volatile("s_waitcnt vmcnt(16)" ::: "memory");   // prev chunk done
        } else {
            asm volatile("s_waitcnt vmcnt(0)" ::: "memory");
        }
        __builtin_amdgcn_sched_barrier(0);
        const int base = WB + (kt & 1) * 8192;
        #pragma unroll
        for (int tt = 0; tt < 2; ++tt) {
            #pragma unroll
            for (int kc = 0; kc < 3; ++kc) {
                const int ro = (tt * 16 + q15) * 128 + (((kc * 4 + hi) ^ l7) * 8);
                const bf16x8 ah = *(const bf16x8*)(smem + base + ro);
                const bf16x8 al = *(const bf16x8*)(smem + base + 4096 + ro);
                sT[kt * 2 + tt] = __builtin_amdgcn_mfma_f32_16x16x32_bf16(ah, qfh[kc], sT[kt * 2 + tt], 0, 0, 0);
                sT[kt * 2 + tt] = __builtin_amdgcn_mfma_f32_16x16x32_bf16(ah, qfl[kc], sT[kt * 2 + tt], 0, 0, 0);
                sT[kt * 2 + tt] = __builtin_amdgcn_mfma_f32_16x16x32_bf16(al, qfh[kc], sT[kt * 2 + tt], 0, 0, 0);
            }
        }
    }

    // early VT stage for chunk 0 (hides under softmax)
    __builtin_amdgcn_sched_barrier(0);
    stageV(0, 0);

    // ---- softmax: temp/mask, 2-wave split-k reduction ----
    float m = -1e30f;
    #pragma unroll
    for (int t = 0; t < 16; ++t) {
        const int4 mv = *(const int4*)&mask_lds[k0 + t * 16 + hi * 4];
        float s;
        s = (mv.x == 0) ? -1e9f : sT[t][0] * temp; sT[t][0] = s; m = fmaxf(m, s);
        s = (mv.y == 0) ? -1e9f : sT[t][1] * temp; sT[t][1] = s; m = fmaxf(m, s);
        s = (mv.z == 0) ? -1e9f : sT[t][2] * temp; sT[t][2] = s; m = fmaxf(m, s);
        s = (mv.w == 0) ? -1e9f : sT[t][3] * temp; sT[t][3] = s; m = fmaxf(m, s);
    }
    m = fmaxf(m, __shfl_xor(m, 16, 64));
    m = fmaxf(m, __shfl_xor(m, 32, 64));
    if (lane < 16) mpart[w][q15] = m;
    __syncthreads();
    const float gm = fmaxf(mpart[0][q15], mpart[1][q15]);
    float sum = 0.0f;
    #pragma unroll
    for (int t = 0; t < 16; ++t) {
        #pragma unroll
        for (int r = 0; r < 4; ++r) {
            const float p = __expf(sT[t][r] - gm);
            sT[t][r] = p;
            sum += p;
        }
    }
    sum += __shfl_xor(sum, 16, 64);
    sum += __shfl_xor(sum, 32, 64);
    if (lane < 16) lpart[w][q15] = sum;
    __syncthreads();
    if (tid < 16) l_final[tid] = lpart[0][tid] + lpart[1][tid];

    // ---- phase 2: PV over wave's k-half, dbuf VT + P in own region ----
    const int PH = WB + 8192, PL = PH + 640;    // P: [16 q][40 u16] hi/lo
    f32x4 acc[4];
    #pragma unroll
    for (int dt = 0; dt < 4; ++dt) acc[dt] = f32x4{0.f, 0.f, 0.f, 0.f};

    #pragma unroll
    for (int c = 0; c < 8; ++c) {
        if (c < 7) {
            stageV(c + 1, (c + 1) & 1);
            asm volatile("s_waitcnt vmcnt(8)" ::: "memory");
        } else {
            asm volatile("s_waitcnt vmcnt(0)" ::: "memory");
        }
        __builtin_amdgcn_sched_barrier(0);
        // write P chunk c (k_local = c*32 .. +32): t-tiles 2c, 2c+1
        #pragma unroll
        for (int tt = 0; tt < 2; ++tt) {
            const int t = c * 2 + tt;
            ushort4 ph, pl;
            u16 hh, ll;
            split2(sT[t][0], hh, ll); ph.x = hh; pl.x = ll;
            split2(sT[t][1], hh, ll); ph.y = hh; pl.y = ll;
            split2(sT[t][2], hh, ll); ph.z = hh; pl.z = ll;
            split2(sT[t][3], hh, ll); ph.w = hh; pl.w = ll;
            const int g  = tt * 2 + (hi >> 1);
            const int po = q15 * 40 + ((g ^ (q15 & 3)) * 8) + (hi & 1) * 4;
            *(ushort4*)(smem + PH + po) = ph;
            *(ushort4*)(smem + PL + po) = pl;
        }
        const int vb  = WB + (c & 1) * 4096;
        const int pro = q15 * 40 + ((hi ^ (q15 & 3)) * 8);
        const bf16x8 pfh = *(const bf16x8*)(smem + PH + pro);
        const bf16x8 pfl = *(const bf16x8*)(smem + PL + pro);
        #pragma unroll
        for (int dt = 0; dt < 4; ++dt) {
            const int vo = (dt * 16 + q15) * 32 + ((hi ^ (q15 & 3)) * 8);
            const bf16x8 vfh = *(const bf16x8*)(smem + vb + vo);
            const bf16x8 vfl = *(const bf16x8*)(smem + vb + 2048 + vo);
            acc[dt] = __builtin_amdgcn_mfma_f32_16x16x32_bf16(pfh, vfh, acc[dt], 0, 0, 0);
            acc[dt] = __builtin_amdgcn_mfma_f32_16x16x32_bf16(pfl, vfh, acc[dt], 0, 0, 0);
            acc[dt] = __builtin_amdgcn_mfma_f32_16x16x32_bf16(pfh, vfl, acc[dt], 0, 0, 0);
        }
    }

    // ---- merge partial acc across waves, epilogue ----
    float* pacc = (float*)(smem + WB + 12288);   // [4 dt][64 lane][4] f32 = 4KB
    #pragma unroll
    for (int dt = 0; dt < 4; ++dt)
        *(f32x4*)&pacc[(dt * 64 + lane) * 4] = acc[dt];
    __syncthreads();
    const float* pa0 = (const float*)(smem + 12288);
    const float* pa1 = (const float*)(smem + 16384 + 12288);
    #pragma unroll
    for (int dd = 0; dd < 2; ++dd) {
        const int dt = w * 2 + dd;
        #pragma unroll
        for (int r = 0; r < 4; ++r) {
            const int idx = (dt * 64 + lane) * 4 + r;
            const float v = (pa0[idx] + pa1[idx]) / l_final[hi * 4 + r];
            u16 hh, ll;
            split2(v, hh, ll);
            const int row = q0 + hi * 4 + r;
            const int col = h * HDIM + dt * 16 + q15;
            chi[row * HIDC + col] = hh;
            clo[row * HIDC + col] = ll;
        }
    }
}

// ---------------- K5: LayerNorm -> out ----------------
__global__ __launch_bounds__(256) void ln_kernel(
    const float* __restrict__ Y, const void* __restrict__ gamma,
    const void* __restrict__ beta, void* __restrict__ out,
    const int* __restrict__ flagp)
{
    const int F = *flagp;
    const int row = blockIdx.x, tid = threadIdx.x;
    float v[4];
    float s = 0.0f, s2 = 0.0f;
    #pragma unroll
    for (int j = 0; j < 4; ++j) {
        v[j] = Y[row * HIDC + tid + j * 256];
        s += v[j]; s2 += v[j] * v[j];
    }
    #pragma unroll
    for (int off = 32; off > 0; off >>= 1) {
        s  += __shfl_xor(s, off, 64);
        s2 += __shfl_xor(s2, off, 64);
    }
    __shared__ float wred[4][2];
    const int w = tid >> 6;
    if ((tid & 63) == 0) { wred[w][0] = s; wred[w][1] = s2; }
    __syncthreads();
    s  = wred[0][0] + wred[1][0] + wred[2][0] + wred[3][0];
    s2 = wred[0][1] + wred[1][1] + wred[2][1] + wred[3][1];
    const float mu   = s / (float)HIDC;
    const float var  = s2 / (float)HIDC - mu * mu;
    const float rstd = rsqrtf(var + 1e-5f);
    #pragma unroll
    for (int j = 0; j < 4; ++j) {
        const int c = tid + j * 256;
        const float g = ldin(gamma, c, F), b = ldin(beta, c, F);
        const float r = (v[j] - mu) * rstd * g + b;
        if (F) ((float*)out)[row * HIDC + c] = r;
        else   ((__hip_bfloat16*)out)[row * HIDC + c] = __float2bfloat16(r);
    }
}

extern "C" void kernel_launch(void* const* d_in, const int* in_sizes, int n_in,
                              void* d_out, int out_size, void* d_ws, size_t ws_size,
                              hipStream_t stream) {
    const void* x    = d_in[0];
    const int*  mask = (const int*)d_in[1];
    const void* Wq   = d_in[2];
    const void* bq   = d_in[3];
    const void* Wk   = d_in[4];
    const void* bk   = d_in[5];
    const void* Wv   = d_in[6];
    const void* bv   = d_in[7];
    const void* Wo   = d_in[8];
    const void* bo   = d_in[9];
    const void* temp = d_in[10];
    const void* gam  = d_in[11];
    const void* bet  = d_in[12];

    float* ws   = (float*)d_ws;
    int*   flag = (int*)ws;                  // 16B reserved
    float* Q    = ws + 4;                    // 512*1024 f32
    float* K    = Q   + SEQ * HIDC;
    float* V    = K   + SEQ * HIDC;
    float* Y    = V   + SEQ * HIDC;          // 512*1024 f32
    u16*   xhi  = (u16*)(Y + SEQ * HIDC);    // 512*1024 bf16 each
    u16*   xlo  = xhi + SEQ * HIDC;
    u16*   chi  = xlo + SEQ * HIDC;
    u16*   clo  = chi + SEQ * HIDC;
    u16*   Wqh  = clo + SEQ * HIDC;          // 8 x 1024*1024 bf16
    u16*   Wql  = Wqh + HIDC * HIDC;
    u16*   Wkh  = Wql + HIDC * HIDC;
    u16*   Wkl  = Wkh + HIDC * HIDC;
    u16*   Wvh  = Wkl + HIDC * HIDC;
    u16*   Wvl  = Wvh + HIDC * HIDC;
    u16*   Woh  = Wvl + HIDC * HIDC;
    u16*   Wol  = Woh + HIDC * HIDC;
    u16*   Qsh  = Wol + HIDC * HIDC;         // 4 x 16*512*128 bf16 (padded spectra)
    u16*   Qsl  = Qsh + NH * SEQ * NFP;
    u16*   Ksh  = Qsl + NH * SEQ * NFP;
    u16*   Ksl  = Ksh + NH * SEQ * NFP;
    u16*   VTh  = Ksl + NH * SEQ * NFP;      // 2 x 16*64*512 bf16
    u16*   VTl  = VTh + NH * HDIM * SEQ;

    sniff_kernel<<<1, 256, 0, stream>>>(Wq, flag);

    // prep: W transpose+split (z<4) + x split (z==4)
    prep_kernel<<<dim3(16, 16, 5), 256, 0, stream>>>(
        Wq, Wk, Wv, Wo, Wqh, Wql, Wkh, Wkl, Wvh, Wvl, Woh, Wol,
        x, xhi, xlo, flag);

    // QKV projection (split-bf16 MFMA, fp32 out)
    mfma3_gemm_kernel<0><<<dim3(24, 8), 256, 0, stream>>>(
        xhi, xlo, Wqh, Wql, Wkh, Wkl, Wvh, Wvl,
        bq, bk, bv, nullptr, Q, K, V, flag);

    // spectra (split-bf16 padded) + V transpose (split-bf16)
    spectral_kernel<<<dim3(SEQ * NH, 2), 64, 0, stream>>>(Q, K, Qsh, Qsl, Ksh, Ksl);
    vtr_kernel<<<dim3(8, 16), 256, 0, stream>>>(V, VTh, VTl);

    // attention (MFMA, k-split + counted-vmcnt dbuf), writes split ctx
    attn_mfma_kernel<<<dim3(SEQ / 16, NH), 128, 0, stream>>>(
        Qsh, Qsl, Ksh, Ksl, VTh, VTl, mask, temp, chi, clo, flag);

    // O-projection (+bias+residual)
    mfma3_gemm_kernel<1><<<dim3(8, 8), 256, 0, stream>>>(
        chi, clo, Woh, Wol, nullptr, nullptr, nullptr, nullptr,
        bo, nullptr, nullptr, x, Y, nullptr, nullptr, flag);

    ln_kernel<<<SEQ, 256, 0, stream>>>(Y, gam, bet, d_out, flag);
}

// Round 6
// 161.563 us; speedup vs baseline: 2.9624x; 1.1273x over previous
//
#include <hip/hip_runtime.h>
#include <hip/hip_bf16.h>
#include <math.h>

constexpr int SEQ   = 512;
constexpr int HIDC  = 1024;
constexpr int NH    = 16;
constexpr int HDIM  = 64;
constexpr int NFREQ = 33;   // rfft bins for n=64
constexpr int NFP   = 128;  // padded packed spectral length (66 -> 128, zero pad)

typedef unsigned short u16;
typedef __bf16 bf16x8 __attribute__((ext_vector_type(8)));
typedef float  f32x4  __attribute__((ext_vector_type(4)));
typedef unsigned short u16x8 __attribute__((ext_vector_type(8)));

typedef __attribute__((address_space(3))) void       as3_void;
typedef __attribute__((address_space(1))) const void as1_void;

// async global->LDS, 16B per lane; LDS dest = wave-uniform base + lane*16
__device__ __forceinline__ void gload16(const u16* g, u16* l) {
    __builtin_amdgcn_global_load_lds((as1_void*)g, (as3_void*)l, 16, 0, 0);
}

// dtype-agnostic input load: f32 ? float : bf16
__device__ __forceinline__ float ldin(const void* p, int i, int f32) {
    if (f32) return ((const float*)p)[i];
    return __bfloat162float(((const __hip_bfloat16*)p)[i]);
}

__device__ __forceinline__ u16 f2b(float f) {   // RNE fp32 -> bf16 bits
    unsigned int u = __builtin_bit_cast(unsigned int, f);
    u += 0x7fffu + ((u >> 16) & 1u);
    return (u16)(u >> 16);
}
__device__ __forceinline__ float b2f(u16 b) {
    return __builtin_bit_cast(float, (unsigned int)b << 16);
}
// fp32 -> (hi, lo) bf16 pair; hi + lo ~ f to ~16 mantissa bits
__device__ __forceinline__ void split2(float f, u16& hi, u16& lo) {
    hi = f2b(f);
    lo = f2b(f - b2f(hi));
}

// inline dtype sniff: wave-uniform, no barrier. bf16 weights have small
// exponents; fp32 seen as bf16 halves shows ~half with exp >= 134.
__device__ __forceinline__ int sniffF(const u16* wq) {
    const int lane = threadIdx.x & 63;
    const ushort4 a = *(const ushort4*)(wq + lane * 8);
    const ushort4 b = *(const ushort4*)(wq + lane * 8 + 4);
    int bad = 0;
    {
        const u16 vs[8] = {a.x, a.y, a.z, a.w, b.x, b.y, b.z, b.w};
        #pragma unroll
        for (int j = 0; j < 8; ++j)
            if (((vs[j] >> 7) & 0xFF) >= 134) bad++;
    }
    #pragma unroll
    for (int off = 32; off > 0; off >>= 1) bad += __shfl_xor(bad, off, 64);
    return (bad > 32) ? 1 : 0;
}

// ---------------- K1a: prep = W transpose+split (z<4) | x split (z==4) ----------------
__global__ __launch_bounds__(256) void prep_kernel(
    const void* __restrict__ W0, const void* __restrict__ W1,
    const void* __restrict__ W2, const void* __restrict__ W3,
    u16* __restrict__ H0, u16* __restrict__ L0,
    u16* __restrict__ H1, u16* __restrict__ L1,
    u16* __restrict__ H2, u16* __restrict__ L2,
    u16* __restrict__ H3, u16* __restrict__ L3,
    const void* __restrict__ xsrc, u16* __restrict__ xhi, u16* __restrict__ xlo)
{
    const int F  = sniffF((const u16*)W0);
    const int mz = blockIdx.z;

    if (mz == 4) {   // x split: 256 blocks x 256 thr x 8 elems
        const int blk = blockIdx.y * 16 + blockIdx.x;
        const int i0  = blk * 2048 + threadIdx.x * 8;
        #pragma unroll
        for (int g = 0; g < 2; ++g) {
            const int i = i0 + g * 4;
            float v[4];
            if (F) {
                const float4 f = *(const float4*)((const float*)xsrc + i);
                v[0] = f.x; v[1] = f.y; v[2] = f.z; v[3] = f.w;
            } else {
                #pragma unroll
                for (int j = 0; j < 4; ++j) v[j] = ldin(xsrc, i + j, 0);
            }
            ushort4 oh, ol;
            u16 h, l;
            split2(v[0], h, l); oh.x = h; ol.x = l;
            split2(v[1], h, l); oh.y = h; ol.y = l;
            split2(v[2], h, l); oh.z = h; ol.z = l;
            split2(v[3], h, l); oh.w = h; ol.w = l;
            *(ushort4*)&xhi[i] = oh;
            *(ushort4*)&xlo[i] = ol;
        }
        return;
    }

    __shared__ float t[64][65];
    const void* W = (mz == 0) ? W0 : (mz == 1) ? W1 : (mz == 2) ? W2 : W3;
    u16* H = (mz == 0) ? H0 : (mz == 1) ? H1 : (mz == 2) ? H2 : H3;
    u16* L = (mz == 0) ? L0 : (mz == 1) ? L1 : (mz == 2) ? L2 : L3;
    const int n0 = blockIdx.x * 64, k0 = blockIdx.y * 64;
    const int tid = threadIdx.x;

    #pragma unroll
    for (int i = 0; i < 4; ++i) {
        const int item = i * 256 + tid;
        const int r = item >> 4, c4 = (item & 15) * 4;
        if (F) {
            const float4 v = *(const float4*)((const float*)W + (k0 + r) * HIDC + n0 + c4);
            t[r][c4 + 0] = v.x; t[r][c4 + 1] = v.y; t[r][c4 + 2] = v.z; t[r][c4 + 3] = v.w;
        } else {
            #pragma unroll
            for (int j = 0; j < 4; ++j)
                t[r][c4 + j] = ldin(W, (k0 + r) * HIDC + n0 + c4 + j, 0);
        }
    }
    __syncthreads();
    #pragma unroll
    for (int i = 0; i < 4; ++i) {
        const int item = i * 256 + tid;
        const int r = item >> 4, c4 = (item & 15) * 4;   // r: n-offset, c4: k-offset
        ushort4 oh, ol;
        u16 h, l;
        split2(t[c4 + 0][r], h, l); oh.x = h; ol.x = l;
        split2(t[c4 + 1][r], h, l); oh.y = h; ol.y = l;
        split2(t[c4 + 2][r], h, l); oh.z = h; ol.z = l;
        split2(t[c4 + 3][r], h, l); oh.w = h; ol.w = l;
        *(ushort4*)&H[(n0 + r) * HIDC + k0 + c4] = oh;
        *(ushort4*)&L[(n0 + r) * HIDC + k0 + c4] = ol;
    }
}

// ---------------- K1c: 3-term split-bf16 MFMA GEMM ----------------
// MODE 0 (MT=64): QKV; grid (24,8). Out: mat0 -> Qmh/Qml split, mat1 -> Kmh/Kml,
//   mat2 -> VTh/VTl transposed split ([h*64+d][s]). bias added pre-split.
// MODE 1 (MT=32): O-proj; grid (8,16). Out: Y fp32 = acc + bias + residual.
template <int MODE, int MT>
__global__ __launch_bounds__(256) void mfma3_gemm_kernel(
    const u16* __restrict__ Ahi, const u16* __restrict__ Alo,
    const u16* __restrict__ B0h, const u16* __restrict__ B0l,
    const u16* __restrict__ B1h, const u16* __restrict__ B1l,
    const u16* __restrict__ B2h, const u16* __restrict__ B2l,
    const void* __restrict__ b0, const void* __restrict__ b1, const void* __restrict__ b2,
    const void* __restrict__ xres,
    u16* __restrict__ Qh, u16* __restrict__ Ql,
    u16* __restrict__ Kh, u16* __restrict__ Kl,
    u16* __restrict__ Vth, u16* __restrict__ Vtl,
    float* __restrict__ Yout,
    const void* __restrict__ wq_sniff)
{
    constexpr int NMI = MT / 16;        // acc row tiles
    constexpr int NAC = MT / 32;        // A chunks per wave
    constexpr int ACH = MT * 64;        // A hi region (u16)
    constexpr int BUF = 2 * ACH + 16384;
    __shared__ __align__(16) u16 smem[2 * BUF];

    const int F    = sniffF((const u16*)wq_sniff);
    const int tid  = threadIdx.x;
    const int lane = tid & 63, wv = tid >> 6;
    const int m0 = blockIdx.y * MT;
    const int n0 = blockIdx.x * 128;

    const u16 *Bh, *Bl; const void* bias; int col0, mat = 0;
    if (MODE == 0) {
        mat  = n0 >> 10;
        col0 = n0 & 1023;
        Bh   = (mat == 0) ? B0h : (mat == 1) ? B1h : B2h;
        Bl   = (mat == 0) ? B0l : (mat == 1) ? B1l : B2l;
        bias = (mat == 0) ? b0  : (mat == 1) ? b1  : b2;
    } else {
        col0 = n0; Bh = B0h; Bl = B0l; bias = b0;
    }

    const int rsub = lane >> 3;
    const int gsw  = ((lane & 7) ^ rsub) * 8;
    const u16* pAh[2]; const u16* pAl[2];
    const u16* pBh[4]; const u16* pBl[4];
    int dA[2], dB[4];
    #pragma unroll
    for (int j = 0; j < NAC; ++j) {
        const int c = wv * NAC + j;
        pAh[j] = Ahi + (m0 + c * 8 + rsub) * HIDC + gsw;
        pAl[j] = Alo + (m0 + c * 8 + rsub) * HIDC + gsw;
        dA[j]  = c * 512;
    }
    #pragma unroll
    for (int j = 0; j < 4; ++j) {
        const int c = wv * 4 + j;
        pBh[j] = Bh + (col0 + c * 8 + rsub) * HIDC + gsw;
        pBl[j] = Bl + (col0 + c * 8 + rsub) * HIDC + gsw;
        dB[j]  = c * 512;
    }

    int g16[2];
    #pragma unroll
    for (int kc = 0; kc < 2; ++kc) g16[kc] = (((kc * 4) + (lane >> 4)) ^ (lane & 7)) * 8;
    int afo[4], bfo[2];
    #pragma unroll
    for (int mi = 0; mi < NMI; ++mi) afo[mi] = (mi * 16 + (lane & 15)) * 64;
    #pragma unroll
    for (int ni = 0; ni < 2; ++ni) bfo[ni] = (wv * 32 + ni * 16 + (lane & 15)) * 64;

    f32x4 acc[NMI][2];
    #pragma unroll
    for (int mi = 0; mi < NMI; ++mi)
        #pragma unroll
        for (int ni = 0; ni < 2; ++ni) acc[mi][ni] = f32x4{0.f, 0.f, 0.f, 0.f};

    #pragma unroll
    for (int j = 0; j < NAC; ++j) {
        gload16(pAh[j], smem + dA[j]);
        gload16(pAl[j], smem + ACH + dA[j]);
    }
    #pragma unroll
    for (int j = 0; j < 4; ++j) {
        gload16(pBh[j], smem + 2 * ACH + dB[j]);
        gload16(pBl[j], smem + 2 * ACH + 8192 + dB[j]);
    }
    __syncthreads();

    for (int t = 0; t < 16; ++t) {
        const int bo = (t & 1) * BUF;
        if (t < 15) {
            const int bn = BUF - bo;
            const int k  = (t + 1) * 64;
            #pragma unroll
            for (int j = 0; j < NAC; ++j) {
                gload16(pAh[j] + k, smem + bn + dA[j]);
                gload16(pAl[j] + k, smem + bn + ACH + dA[j]);
            }
            #pragma unroll
            for (int j = 0; j < 4; ++j) {
                gload16(pBh[j] + k, smem + bn + 2 * ACH + dB[j]);
                gload16(pBl[j] + k, smem + bn + 2 * ACH + 8192 + dB[j]);
            }
        }
        #pragma unroll
        for (int kc = 0; kc < 2; ++kc) {
            bf16x8 ah[NMI], al[NMI], bh2[2], bl2[2];
            #pragma unroll
            for (int mi = 0; mi < NMI; ++mi) {
                ah[mi] = *(const bf16x8*)(smem + bo +       afo[mi] + g16[kc]);
                al[mi] = *(const bf16x8*)(smem + bo + ACH + afo[mi] + g16[kc]);
            }
            #pragma unroll
            for (int ni = 0; ni < 2; ++ni) {
                bh2[ni] = *(const bf16x8*)(smem + bo + 2 * ACH +        bfo[ni] + g16[kc]);
                bl2[ni] = *(const bf16x8*)(smem + bo + 2 * ACH + 8192 + bfo[ni] + g16[kc]);
            }
            #pragma unroll
            for (int mi = 0; mi < NMI; ++mi)
                #pragma unroll
                for (int ni = 0; ni < 2; ++ni) {
                    acc[mi][ni] = __builtin_amdgcn_mfma_f32_16x16x32_bf16(
                        ah[mi], bh2[ni], acc[mi][ni], 0, 0, 0);
                    acc[mi][ni] = __builtin_amdgcn_mfma_f32_16x16x32_bf16(
                        ah[mi], bl2[ni], acc[mi][ni], 0, 0, 0);
                    acc[mi][ni] = __builtin_amdgcn_mfma_f32_16x16x32_bf16(
                        al[mi], bh2[ni], acc[mi][ni], 0, 0, 0);
                }
        }
        __syncthreads();
    }

    // epilogue: C row = (lane>>4)*4 + r, col = lane&15 (harness-verified)
    const int hi4 = (lane >> 4) * 4;
    #pragma unroll
    for (int ni = 0; ni < 2; ++ni) {
        const int col = col0 + wv * 32 + ni * 16 + (lane & 15);
        const float bval = ldin(bias, col, F);
        #pragma unroll
        for (int mi = 0; mi < NMI; ++mi) {
            const int row0 = m0 + mi * 16 + hi4;
            if (MODE == 1) {
                #pragma unroll
                for (int r = 0; r < 4; ++r) {
                    const int row = row0 + r;
                    Yout[row * HIDC + col] =
                        acc[mi][ni][r] + bval + ldin(xres, row * HIDC + col, F);
                }
            } else if (mat == 2) {
                // V: transposed split store VT[col][row0..row0+3]
                ushort4 oh, ol;
                u16 h_, l_;
                split2(acc[mi][ni][0] + bval, h_, l_); oh.x = h_; ol.x = l_;
                split2(acc[mi][ni][1] + bval, h_, l_); oh.y = h_; ol.y = l_;
                split2(acc[mi][ni][2] + bval, h_, l_); oh.z = h_; ol.z = l_;
                split2(acc[mi][ni][3] + bval, h_, l_); oh.w = h_; ol.w = l_;
                *(ushort4*)&Vth[col * SEQ + row0] = oh;
                *(ushort4*)&Vtl[col * SEQ + row0] = ol;
            } else {
                u16* Oh = (mat == 0) ? Qh : Kh;
                u16* Ol = (mat == 0) ? Ql : Kl;
                #pragma unroll
                for (int r = 0; r < 4; ++r) {
                    u16 h_, l_;
                    split2(acc[mi][ni][r] + bval, h_, l_);
                    Oh[(row0 + r) * HIDC + col] = h_;
                    Ol[(row0 + r) * HIDC + col] = l_;
                }
            }
        }
    }
}

// ---------------- K2: DFT-as-MFMA + amplitude normalize + pad + split ----------------
// In: Qm/Km split bf16 [512][1024] viewed as [8192 rows (s*16+h)][64 d].
// C[8192][66] = A @ D (D built in-register from sincos table, split-bf16, 3-term).
// Epilogue: per row, a_f = sqrt(re^2+im^2); out = (re,im)/sqrt(a); pad 66..127 = 0.
// Out layout: [(h*SEQ+s)*NFP + f]  (matches attn staging).
__global__ __launch_bounds__(256) void dft_kernel(
    const u16* __restrict__ Qmh, const u16* __restrict__ Qml,
    const u16* __restrict__ Kmh, const u16* __restrict__ Kml,
    u16* __restrict__ Qsh, u16* __restrict__ Qsl,
    u16* __restrict__ Ksh, u16* __restrict__ Ksl)
{
    __shared__ __align__(16) u16 smem[16384];   // stage: Ah@0, Al@4096; then C f32[64][128]
    __shared__ float tcos[64], tsin[64];

    const int tid  = threadIdx.x;
    const int lane = tid & 63, wv = tid >> 6;
    const int hi = lane >> 4, q15 = lane & 15, l7 = lane & 7;
    const int m0  = blockIdx.x * 64;
    const int sel = blockIdx.y;
    const u16* Ah_g = sel ? Kmh : Qmh;
    const u16* Al_g = sel ? Kml : Qml;
    u16* Oh = sel ? Ksh : Qsh;
    u16* Ol = sel ? Ksl : Qsl;

    // stage A tile (64 rows x 64 k), same swizzle as GEMM
    const int rsub = lane >> 3;
    const int gsw  = ((lane & 7) ^ rsub) * 8;
    #pragma unroll
    for (int j = 0; j < 2; ++j) {
        const int c = wv * 2 + j;
        gload16(Ah_g + (m0 + c * 8 + rsub) * 64 + gsw, smem + c * 512);
        gload16(Al_g + (m0 + c * 8 + rsub) * 64 + gsw, smem + 4096 + c * 512);
    }
    if (tid < 64) {
        float sv, cv;
        sincosf((float)tid * (6.283185307179586f / 64.0f), &sv, &cv);
        tcos[tid] = cv; tsin[tid] = sv;
    }
    __syncthreads();   // drains gload vmcnt + publishes tables

    // D fragments: entity col c = wv*32 + ni*16 + q15; k-granule (kc*4+hi)
    bf16x8 Dh[2][2], Dl[2][2];
    #pragma unroll
    for (int ni = 0; ni < 2; ++ni) {
        const int c = wv * 32 + ni * 16 + q15;
        #pragma unroll
        for (int kc = 0; kc < 2; ++kc) {
            u16x8 bh_, bl_;
            #pragma unroll
            for (int e = 0; e < 8; ++e) {
                const int k = (kc * 4 + hi) * 8 + e;
                float dv;
                if (c < 33)      dv = tcos[(c * k) & 63];
                else if (c < 66) dv = -tsin[((c - 33) * k) & 63];
                else             dv = 0.0f;
                u16 h_, l_;
                split2(dv, h_, l_);
                bh_[e] = h_; bl_[e] = l_;
            }
            Dh[ni][kc] = __builtin_bit_cast(bf16x8, bh_);
            Dl[ni][kc] = __builtin_bit_cast(bf16x8, bl_);
        }
    }

    f32x4 acc[4][2];
    #pragma unroll
    for (int mi = 0; mi < 4; ++mi)
        #pragma unroll
        for (int ni = 0; ni < 2; ++ni) acc[mi][ni] = f32x4{0.f, 0.f, 0.f, 0.f};

    #pragma unroll
    for (int kc = 0; kc < 2; ++kc) {
        const int g = (((kc * 4) + hi) ^ l7) * 8;
        bf16x8 ah[4], al[4];
        #pragma unroll
        for (int mi = 0; mi < 4; ++mi) {
            ah[mi] = *(const bf16x8*)(smem +        (mi * 16 + q15) * 64 + g);
            al[mi] = *(const bf16x8*)(smem + 4096 + (mi * 16 + q15) * 64 + g);
        }
        #pragma unroll
        for (int mi = 0; mi < 4; ++mi)
            #pragma unroll
            for (int ni = 0; ni < 2; ++ni) {
                acc[mi][ni] = __builtin_amdgcn_mfma_f32_16x16x32_bf16(
                    ah[mi], Dh[ni][kc], acc[mi][ni], 0, 0, 0);
                acc[mi][ni] = __builtin_amdgcn_mfma_f32_16x16x32_bf16(
                    ah[mi], Dl[ni][kc], acc[mi][ni], 0, 0, 0);
                acc[mi][ni] = __builtin_amdgcn_mfma_f32_16x16x32_bf16(
                    al[mi], Dh[ni][kc], acc[mi][ni], 0, 0, 0);
            }
    }
    __syncthreads();   // A reads done; reuse smem as C

    float* Cl = (float*)smem;   // [64][128]
    #pragma unroll
    for (int mi = 0; mi < 4; ++mi)
        #pragma unroll
        for (int ni = 0; ni < 2; ++ni)
            #pragma unroll
            for (int r = 0; r < 4; ++r)
                Cl[(mi * 16 + hi * 4 + r) * 128 + wv * 32 + ni * 16 + q15] = acc[mi][ni][r];
    __syncthreads();

    // normalize + split + pad; 4 threads/row, 32 f each
    const int row = tid >> 2, tf = tid & 3;
    const int g   = m0 + row;
    const int ss  = g >> 4, hh = g & 15;
    u16 vh[32], vl[32];
    #pragma unroll
    for (int j = 0; j < 32; ++j) {
        const int f = tf * 32 + j;
        float val = 0.0f;
        if (f < 66) {
            const int fb = (f < 33) ? f : (f - 33);
            const float re = Cl[row * 128 + fb];
            const float im = Cl[row * 128 + 33 + fb];
            const float a  = sqrtf(re * re + im * im);
            const float sc = (a > 0.0f) ? rsqrtf(a) : 0.0f;
            val = ((f < 33) ? re : im) * sc;
        }
        split2(val, vh[j], vl[j]);
    }
    const int obase = (hh * SEQ + ss) * NFP + tf * 32;
    #pragma unroll
    for (int j4 = 0; j4 < 8; ++j4) {
        ushort4 oh, ol;
        oh.x = vh[j4 * 4 + 0]; oh.y = vh[j4 * 4 + 1]; oh.z = vh[j4 * 4 + 2]; oh.w = vh[j4 * 4 + 3];
        ol.x = vl[j4 * 4 + 0]; ol.y = vl[j4 * 4 + 1]; ol.z = vl[j4 * 4 + 2]; ol.w = vl[j4 * 4 + 3];
        *(ushort4*)&Oh[obase + j4 * 4] = oh;
        *(ushort4*)&Ol[obase + j4 * 4] = ol;
    }
}

// ---------------- K3: MFMA attention (unchanged structure, inline sniff) ----------------
__global__ __launch_bounds__(128) void attn_mfma_kernel(
    const u16* __restrict__ Qsh, const u16* __restrict__ Qsl,
    const u16* __restrict__ Ksh, const u16* __restrict__ Ksl,
    const u16* __restrict__ VTh, const u16* __restrict__ VTl,
    const int* __restrict__ mask, const void* __restrict__ temp_p,
    u16* __restrict__ chi, u16* __restrict__ clo,
    const void* __restrict__ wq_sniff)
{
    __shared__ __align__(16) u16 smem[32768];   // 64 KB: wave w owns [w*16384, +16384)
    __shared__ int   mask_lds[512];
    __shared__ float mpart[2][16], lpart[2][16], l_final[16];

    const int F    = sniffF((const u16*)wq_sniff);
    const int tid  = threadIdx.x;
    const int lane = tid & 63, w = tid >> 6;
    const int hi = lane >> 4, q15 = lane & 15, l7 = lane & 7;
    const int h  = blockIdx.y, q0 = blockIdx.x * 16;
    const int k0 = w * 256;                     // wave's k-half
    const int WB = w * 16384;                   // wave's LDS region (u16)
    const float temp = ldin(temp_p, 0, F);

    *(int4*)&mask_lds[tid * 4] = *(const int4*)&mask[tid * 4];

    bf16x8 qfh[3], qfl[3];
    {
        const int qrow = (h * SEQ + q0 + q15) * NFP;
        #pragma unroll
        for (int kc = 0; kc < 3; ++kc) {
            qfh[kc] = *(const bf16x8*)(Qsh + qrow + kc * 32 + hi * 8);
            qfl[kc] = *(const bf16x8*)(Qsl + qrow + kc * 32 + hi * 8);
        }
    }

    const int rc4 = lane >> 4;

    auto stageK = [&](int kt, int b) {
        const int base = WB + b * 8192;
        #pragma unroll
        for (int j = 0; j < 8; ++j) {
            const int row = j * 4 + rc4;
            const int gs  = (q15 ^ (row & 7)) * 8;
            const int so  = (h * SEQ + k0 + kt * 32 + row) * NFP + gs;
            gload16(Ksh + so, smem + base + j * 512);
            gload16(Ksl + so, smem + base + 4096 + j * 512);
        }
    };
    auto stageV = [&](int c, int b) {
        const int base = WB + b * 4096;
        #pragma unroll
        for (int j = 0; j < 4; ++j) {
            const int d  = j * 16 + (lane >> 2);
            const int gs = ((lane & 3) ^ (d & 3)) * 8;
            const int so = (h * HDIM + d) * SEQ + k0 + c * 32 + gs;
            gload16(VTh + so, smem + base + j * 512);
            gload16(VTl + so, smem + base + 2048 + j * 512);
        }
    };

    f32x4 sT[16];
    #pragma unroll
    for (int t = 0; t < 16; ++t) sT[t] = f32x4{0.f, 0.f, 0.f, 0.f};

    stageK(0, 0);
    #pragma unroll
    for (int kt = 0; kt < 8; ++kt) {
        if (kt < 7) {
            stageK(kt + 1, (kt + 1) & 1);
            asm volatile("s_waitcnt vmcnt(16)" ::: "memory");
        } else {
            asm volatile("s_waitcnt vmcnt(0)" ::: "memory");
        }
        __builtin_amdgcn_sched_barrier(0);
        const int base = WB + (kt & 1) * 8192;
        #pragma unroll
        for (int tt = 0; tt < 2; ++tt) {
            #pragma unroll
            for (int kc = 0; kc < 3; ++kc) {
                const int ro = (tt * 16 + q15) * 128 + (((kc * 4 + hi) ^ l7) * 8);
                const bf16x8 ah = *(const bf16x8*)(smem + base + ro);
                const bf16x8 al = *(const bf16x8*)(smem + base + 4096 + ro);
                sT[kt * 2 + tt] = __builtin_amdgcn_mfma_f32_16x16x32_bf16(ah, qfh[kc], sT[kt * 2 + tt], 0, 0, 0);
                sT[kt * 2 + tt] = __builtin_amdgcn_mfma_f32_16x16x32_bf16(ah, qfl[kc], sT[kt * 2 + tt], 0, 0, 0);
                sT[kt * 2 + tt] = __builtin_amdgcn_mfma_f32_16x16x32_bf16(al, qfh[kc], sT[kt * 2 + tt], 0, 0, 0);
            }
        }
    }

    __builtin_amdgcn_sched_barrier(0);
    stageV(0, 0);

    float m = -1e30f;
    #pragma unroll
    for (int t = 0; t < 16; ++t) {
        const int4 mv = *(const int4*)&mask_lds[k0 + t * 16 + hi * 4];
        float s;
        s = (mv.x == 0) ? -1e9f : sT[t][0] * temp; sT[t][0] = s; m = fmaxf(m, s);
        s = (mv.y == 0) ? -1e9f : sT[t][1] * temp; sT[t][1] = s; m = fmaxf(m, s);
        s = (mv.z == 0) ? -1e9f : sT[t][2] * temp; sT[t][2] = s; m = fmaxf(m, s);
        s = (mv.w == 0) ? -1e9f : sT[t][3] * temp; sT[t][3] = s; m = fmaxf(m, s);
    }
    m = fmaxf(m, __shfl_xor(m, 16, 64));
    m = fmaxf(m, __shfl_xor(m, 32, 64));
    if (lane < 16) mpart[w][q15] = m;
    __syncthreads();
    const float gm = fmaxf(mpart[0][q15], mpart[1][q15]);
    float sum = 0.0f;
    #pragma unroll
    for (int t = 0; t < 16; ++t) {
        #pragma unroll
        for (int r = 0; r < 4; ++r) {
            const float p = __expf(sT[t][r] - gm);
            sT[t][r] = p;
            sum += p;
        }
    }
    sum += __shfl_xor(sum, 16, 64);
    sum += __shfl_xor(sum, 32, 64);
    if (lane < 16) lpart[w][q15] = sum;
    __syncthreads();
    if (tid < 16) l_final[tid] = lpart[0][tid] + lpart[1][tid];

    const int PH = WB + 8192, PL = PH + 640;
    f32x4 acc[4];
    #pragma unroll
    for (int dt = 0; dt < 4; ++dt) acc[dt] = f32x4{0.f, 0.f, 0.f, 0.f};

    #pragma unroll
    for (int c = 0; c < 8; ++c) {
        if (c < 7) {
            stageV(c + 1, (c + 1) & 1);
            asm volatile("s_waitcnt vmcnt(8)" ::: "memory");
        } else {
            asm volatile("s_waitcnt vmcnt(0)" ::: "memory");
        }
        __builtin_amdgcn_sched_barrier(0);
        #pragma unroll
        for (int tt = 0; tt < 2; ++tt) {
            const int t = c * 2 + tt;
            ushort4 ph, pl;
            u16 hh, ll;
            split2(sT[t][0], hh, ll); ph.x = hh; pl.x = ll;
            split2(sT[t][1], hh, ll); ph.y = hh; pl.y = ll;
            split2(sT[t][2], hh, ll); ph.z = hh; pl.z = ll;
            split2(sT[t][3], hh, ll); ph.w = hh; pl.w = ll;
            const int g  = tt * 2 + (hi >> 1);
            const int po = q15 * 40 + ((g ^ (q15 & 3)) * 8) + (hi & 1) * 4;
            *(ushort4*)(smem + PH + po) = ph;
            *(ushort4*)(smem + PL + po) = pl;
        }
        const int vb  = WB + (c & 1) * 4096;
        const int pro = q15 * 40 + ((hi ^ (q15 & 3)) * 8);
        const bf16x8 pfh = *(const bf16x8*)(smem + PH + pro);
        const bf16x8 pfl = *(const bf16x8*)(smem + PL + pro);
        #pragma unroll
        for (int dt = 0; dt < 4; ++dt) {
            const int vo = (dt * 16 + q15) * 32 + ((hi ^ (q15 & 3)) * 8);
            const bf16x8 vfh = *(const bf16x8*)(smem + vb + vo);
            const bf16x8 vfl = *(const bf16x8*)(smem + vb + 2048 + vo);
            acc[dt] = __builtin_amdgcn_mfma_f32_16x16x32_bf16(pfh, vfh, acc[dt], 0, 0, 0);
            acc[dt] = __builtin_amdgcn_mfma_f32_16x16x32_bf16(pfl, vfh, acc[dt], 0, 0, 0);
            acc[dt] = __builtin_amdgcn_mfma_f32_16x16x32_bf16(pfh, vfl, acc[dt], 0, 0, 0);
        }
    }

    float* pacc = (float*)(smem + WB + 12288);
    #pragma unroll
    for (int dt = 0; dt < 4; ++dt)
        *(f32x4*)&pacc[(dt * 64 + lane) * 4] = acc[dt];
    __syncthreads();
    const float* pa0 = (const float*)(smem + 12288);
    const float* pa1 = (const float*)(smem + 16384 + 12288);
    #pragma unroll
    for (int dd = 0; dd < 2; ++dd) {
        const int dt = w * 2 + dd;
        #pragma unroll
        for (int r = 0; r < 4; ++r) {
            const int idx = (dt * 64 + lane) * 4 + r;
            const float v = (pa0[idx] + pa1[idx]) / l_final[hi * 4 + r];
            u16 hh, ll;
            split2(v, hh, ll);
            const int row = q0 + hi * 4 + r;
            const int col = h * HDIM + dt * 16 + q15;
            chi[row * HIDC + col] = hh;
            clo[row * HIDC + col] = ll;
        }
    }
}

// ---------------- K5: LayerNorm -> out ----------------
__global__ __launch_bounds__(256) void ln_kernel(
    const float* __restrict__ Y, const void* __restrict__ gamma,
    const void* __restrict__ beta, void* __restrict__ out,
    const void* __restrict__ wq_sniff)
{
    const int F = sniffF((const u16*)wq_sniff);
    const int row = blockIdx.x, tid = threadIdx.x;
    float v[4];
    float s = 0.0f, s2 = 0.0f;
    #pragma unroll
    for (int j = 0; j < 4; ++j) {
        v[j] = Y[row * HIDC + tid + j * 256];
        s += v[j]; s2 += v[j] * v[j];
    }
    #pragma unroll
    for (int off = 32; off > 0; off >>= 1) {
        s  += __shfl_xor(s, off, 64);
        s2 += __shfl_xor(s2, off, 64);
    }
    __shared__ float wred[4][2];
    const int w = tid >> 6;
    if ((tid & 63) == 0) { wred[w][0] = s; wred[w][1] = s2; }
    __syncthreads();
    s  = wred[0][0] + wred[1][0] + wred[2][0] + wred[3][0];
    s2 = wred[0][1] + wred[1][1] + wred[2][1] + wred[3][1];
    const float mu   = s / (float)HIDC;
    const float var  = s2 / (float)HIDC - mu * mu;
    const float rstd = rsqrtf(var + 1e-5f);
    #pragma unroll
    for (int j = 0; j < 4; ++j) {
        const int c = tid + j * 256;
        const float g = ldin(gamma, c, F), b = ldin(beta, c, F);
        const float r = (v[j] - mu) * rstd * g + b;
        if (F) ((float*)out)[row * HIDC + c] = r;
        else   ((__hip_bfloat16*)out)[row * HIDC + c] = __float2bfloat16(r);
    }
}

extern "C" void kernel_launch(void* const* d_in, const int* in_sizes, int n_in,
                              void* d_out, int out_size, void* d_ws, size_t ws_size,
                              hipStream_t stream) {
    const void* x    = d_in[0];
    const int*  mask = (const int*)d_in[1];
    const void* Wq   = d_in[2];
    const void* bq   = d_in[3];
    const void* Wk   = d_in[4];
    const void* bk   = d_in[5];
    const void* Wv   = d_in[6];
    const void* bv   = d_in[7];
    const void* Wo   = d_in[8];
    const void* bo   = d_in[9];
    const void* temp = d_in[10];
    const void* gam  = d_in[11];
    const void* bet  = d_in[12];

    float* Y    = (float*)d_ws;              // 512*1024 f32
    u16*   xhi  = (u16*)(Y + SEQ * HIDC);    // each 512*1024 u16
    u16*   xlo  = xhi + SEQ * HIDC;
    u16*   chi  = xlo + SEQ * HIDC;
    u16*   clo  = chi + SEQ * HIDC;
    u16*   Qmh  = clo + SEQ * HIDC;
    u16*   Qml  = Qmh + SEQ * HIDC;
    u16*   Kmh  = Qml + SEQ * HIDC;
    u16*   Kml  = Kmh + SEQ * HIDC;
    u16*   VTh  = Kml + SEQ * HIDC;          // [h*64+d][s]
    u16*   VTl  = VTh + NH * HDIM * SEQ;
    u16*   Wqh  = VTl + NH * HDIM * SEQ;     // 8 x 1024*1024
    u16*   Wql  = Wqh + HIDC * HIDC;
    u16*   Wkh  = Wql + HIDC * HIDC;
    u16*   Wkl  = Wkh + HIDC * HIDC;
    u16*   Wvh  = Wkl + HIDC * HIDC;
    u16*   Wvl  = Wvh + HIDC * HIDC;
    u16*   Woh  = Wvl + HIDC * HIDC;
    u16*   Wol  = Woh + HIDC * HIDC;
    u16*   Qsh  = Wol + HIDC * HIDC;         // 4 x 16*512*128
    u16*   Qsl  = Qsh + NH * SEQ * NFP;
    u16*   Ksh  = Qsl + NH * SEQ * NFP;
    u16*   Ksl  = Ksh + NH * SEQ * NFP;

    // prep: W transpose+split (z<4) + x split (z==4); dtype sniffed inline
    prep_kernel<<<dim3(16, 16, 5), 256, 0, stream>>>(
        Wq, Wk, Wv, Wo, Wqh, Wql, Wkh, Wkl, Wvh, Wvl, Woh, Wol,
        x, xhi, xlo);

    // QKV projection: Q,K -> split bf16; V -> transposed split bf16
    mfma3_gemm_kernel<0, 64><<<dim3(24, 8), 256, 0, stream>>>(
        xhi, xlo, Wqh, Wql, Wkh, Wkl, Wvh, Wvl,
        bq, bk, bv, nullptr,
        Qmh, Qml, Kmh, Kml, VTh, VTl, nullptr, Wq);

    // DFT (MFMA) + normalize + pad + split -> Qs/Ks
    dft_kernel<<<dim3(128, 2), 256, 0, stream>>>(
        Qmh, Qml, Kmh, Kml, Qsh, Qsl, Ksh, Ksl);

    // attention (MFMA, k-split + counted-vmcnt dbuf), writes split ctx
    attn_mfma_kernel<<<dim3(SEQ / 16, NH), 128, 0, stream>>>(
        Qsh, Qsl, Ksh, Ksl, VTh, VTl, mask, temp, chi, clo, Wq);

    // O-projection (+bias+residual), MT=32 for 128-block occupancy
    mfma3_gemm_kernel<1, 32><<<dim3(8, 16), 256, 0, stream>>>(
        chi, clo, Woh, Wol, nullptr, nullptr, nullptr, nullptr,
        bo, nullptr, nullptr, x,
        nullptr, nullptr, nullptr, nullptr, nullptr, nullptr, Y, Wq);

    ln_kernel<<<SEQ, 256, 0, stream>>>(Y, gam, bet, d_out, Wq);
}